// Round 1
// baseline (1810.658 us; speedup 1.0000x reference)
//
#include <hip/hip_runtime.h>
#include <hip/hip_bf16.h>

#define N_NODES 100000
#define N_EDGES 1600000
#define F_IN    512
#define HID     64
#define NCLS    16

// ---------------------------------------------------------------------------
// zero-fill (float4 grid-stride)
// ---------------------------------------------------------------------------
__global__ void zerok(float4* __restrict__ p, int n4) {
    int i = blockIdx.x * blockDim.x + threadIdx.x;
    int stride = gridDim.x * blockDim.x;
    for (; i < n4; i += stride) p[i] = make_float4(0.f, 0.f, 0.f, 0.f);
}

// ---------------------------------------------------------------------------
// GEMM1: support = x @ W1   [N,512] @ [512,64] -> [N,64], fp32 vector ALU
// block = 256 threads, tile 64 rows x 64 cols, K staged in chunks of 32.
// Thread (tx=t&15, ty=t>>4) owns 4 rows x 4 cols -> 16 FMA per k.
// ---------------------------------------------------------------------------
__global__ __launch_bounds__(256) void gemm1(const float* __restrict__ x,
                                             const float* __restrict__ W1,
                                             float* __restrict__ support) {
    __shared__ float xs[32][68];   // [k][row], padded to 68 (16B-aligned rows, conflict-safe)
    __shared__ float ws[32][64];   // [k][col], flat-contiguous for staging

    const int tid  = threadIdx.x;
    const int tx   = tid & 15;     // col group: cols tx*4 .. tx*4+3
    const int ty   = tid >> 4;     // row group: rows ty*4 .. ty*4+3
    const int row0 = blockIdx.x * 64;

    float acc[4][4] = {};

    for (int kb = 0; kb < F_IN; kb += 32) {
        // --- stage W1 chunk: rows kb..kb+31, contiguous 2048 floats ---
        {
            const float4* wsrc = (const float4*)(W1 + kb * 64);
            float4* wdst = (float4*)(&ws[0][0]);
            wdst[tid]       = wsrc[tid];
            wdst[tid + 256] = wsrc[tid + 256];
        }
        // --- stage x chunk transposed: 64 rows x 32 k ---
        #pragma unroll
        for (int li = 0; li < 2; li++) {
            int l   = tid + li * 256;       // 0..511 float4 slots
            int row = l >> 3;               // 8 float4 per row
            int kk  = (l & 7) * 4;
            float4 v = make_float4(0.f, 0.f, 0.f, 0.f);
            if (row0 + row < N_NODES)
                v = *(const float4*)(x + (long)(row0 + row) * F_IN + kb + kk);
            xs[kk + 0][row] = v.x;
            xs[kk + 1][row] = v.y;
            xs[kk + 2][row] = v.z;
            xs[kk + 3][row] = v.w;
        }
        __syncthreads();

        #pragma unroll
        for (int k = 0; k < 32; k++) {
            float4 xv = *(const float4*)&xs[k][ty * 4];
            float4 wv = *(const float4*)&ws[k][tx * 4];
            acc[0][0] += xv.x * wv.x; acc[0][1] += xv.x * wv.y;
            acc[0][2] += xv.x * wv.z; acc[0][3] += xv.x * wv.w;
            acc[1][0] += xv.y * wv.x; acc[1][1] += xv.y * wv.y;
            acc[1][2] += xv.y * wv.z; acc[1][3] += xv.y * wv.w;
            acc[2][0] += xv.z * wv.x; acc[2][1] += xv.z * wv.y;
            acc[2][2] += xv.z * wv.z; acc[2][3] += xv.z * wv.w;
            acc[3][0] += xv.w * wv.x; acc[3][1] += xv.w * wv.y;
            acc[3][2] += xv.w * wv.z; acc[3][3] += xv.w * wv.w;
        }
        __syncthreads();
    }

    #pragma unroll
    for (int r = 0; r < 4; r++) {
        int row = row0 + ty * 4 + r;
        if (row < N_NODES) {
            float4 o = make_float4(acc[r][0], acc[r][1], acc[r][2], acc[r][3]);
            *(float4*)(support + (long)row * HID + tx * 4) = o;
        }
    }
}

// ---------------------------------------------------------------------------
// SPMM1: h[dst] += val * support[src], D=64. 16 threads per edge (float4).
// ---------------------------------------------------------------------------
__global__ __launch_bounds__(256) void spmm1(const int* __restrict__ esrc,
                                             const int* __restrict__ edst,
                                             const float* __restrict__ eval_,
                                             const float* __restrict__ sup,
                                             float* __restrict__ h) {
    int gid = blockIdx.x * 256 + threadIdx.x;
    int e   = gid >> 4;
    int c4  = (gid & 15) * 4;
    if (e >= N_EDGES) return;
    int   s = esrc[e];
    int   d = edst[e];
    float v = eval_[e];
    float4 g = *(const float4*)(sup + (long)s * HID + c4);
    float* hp = h + (long)d * HID + c4;
    atomicAdd(hp + 0, g.x * v);
    atomicAdd(hp + 1, g.y * v);
    atomicAdd(hp + 2, g.z * v);
    atomicAdd(hp + 3, g.w * v);
}

// ---------------------------------------------------------------------------
// ReLU(h + b1) @ W2 -> sup2  [N,64]@[64,16]. 16 threads per node.
// ---------------------------------------------------------------------------
__global__ __launch_bounds__(256) void relu_gemm2(const float* __restrict__ h,
                                                  const float* __restrict__ b1,
                                                  const float* __restrict__ W2,
                                                  float* __restrict__ sup2) {
    __shared__ float w2s[HID * NCLS];
    __shared__ float b1s[HID];
    int tid = threadIdx.x;
    for (int i = tid; i < HID * NCLS; i += 256) w2s[i] = W2[i];
    if (tid < HID) b1s[tid] = b1[tid];
    __syncthreads();

    int node = blockIdx.x * 16 + (tid >> 4);
    int c    = tid & 15;
    if (node >= N_NODES) return;
    const float* hr = h + (long)node * HID;
    float acc = 0.f;
    #pragma unroll
    for (int k = 0; k < HID; k++) {
        float hv = fmaxf(hr[k] + b1s[k], 0.f);
        acc += hv * w2s[k * NCLS + c];
    }
    sup2[(long)node * NCLS + c] = acc;
}

// ---------------------------------------------------------------------------
// SPMM2: out[dst] += val * sup2[src], D=16. 4 threads per edge (float4).
// ---------------------------------------------------------------------------
__global__ __launch_bounds__(256) void spmm2(const int* __restrict__ esrc,
                                             const int* __restrict__ edst,
                                             const float* __restrict__ eval_,
                                             const float* __restrict__ sup2,
                                             float* __restrict__ out) {
    int gid = blockIdx.x * 256 + threadIdx.x;
    int e   = gid >> 2;
    int c4  = (gid & 3) * 4;
    if (e >= N_EDGES) return;
    int   s = esrc[e];
    int   d = edst[e];
    float v = eval_[e];
    float4 g = *(const float4*)(sup2 + (long)s * NCLS + c4);
    float* op = out + (long)d * NCLS + c4;
    atomicAdd(op + 0, g.x * v);
    atomicAdd(op + 1, g.y * v);
    atomicAdd(op + 2, g.z * v);
    atomicAdd(op + 3, g.w * v);
}

// ---------------------------------------------------------------------------
// softmax over 16 classes per node (adds b2 first). 1 thread per node.
// ---------------------------------------------------------------------------
__global__ __launch_bounds__(256) void softmax_k(float* __restrict__ out,
                                                 const float* __restrict__ b2) {
    __shared__ float b2s[NCLS];
    if (threadIdx.x < NCLS) b2s[threadIdx.x] = b2[threadIdx.x];
    __syncthreads();
    int n = blockIdx.x * 256 + threadIdx.x;
    if (n >= N_NODES) return;
    float* p = out + (long)n * NCLS;
    float v[NCLS];
    #pragma unroll
    for (int i = 0; i < NCLS; i++) v[i] = p[i] + b2s[i];
    float m = v[0];
    #pragma unroll
    for (int i = 1; i < NCLS; i++) m = fmaxf(m, v[i]);
    float sum = 0.f;
    #pragma unroll
    for (int i = 0; i < NCLS; i++) { v[i] = expf(v[i] - m); sum += v[i]; }
    float inv = 1.f / sum;
    #pragma unroll
    for (int i = 0; i < NCLS; i++) p[i] = v[i] * inv;
}

// ---------------------------------------------------------------------------
extern "C" void kernel_launch(void* const* d_in, const int* in_sizes, int n_in,
                              void* d_out, int out_size, void* d_ws, size_t ws_size,
                              hipStream_t stream) {
    const float* x     = (const float*)d_in[0];
    const int*   esrc  = (const int*)  d_in[1];
    const int*   edst  = (const int*)  d_in[2];
    const float* eval_ = (const float*)d_in[3];
    const float* W1    = (const float*)d_in[4];
    const float* b1    = (const float*)d_in[5];
    const float* W2    = (const float*)d_in[6];
    const float* b2    = (const float*)d_in[7];
    float* out = (float*)d_out;

    float* sup1 = (float*)d_ws;                       // 100000*64 = 6.4M floats
    float* h    = sup1 + (long)N_NODES * HID;         // 6.4M floats
    float* sup2 = h    + (long)N_NODES * HID;         // 1.6M floats
    // total ws use: 14.4M floats = 57.6 MB

    // zero h and out (accumulation targets)
    zerok<<<2048, 256, 0, stream>>>((float4*)h, N_NODES * HID / 4);
    zerok<<<2048, 256, 0, stream>>>((float4*)out, N_NODES * NCLS / 4);

    // layer 1
    gemm1<<<(N_NODES + 63) / 64, 256, 0, stream>>>(x, W1, sup1);
    spmm1<<<(N_EDGES * 16) / 256, 256, 0, stream>>>(esrc, edst, eval_, sup1, h);

    // layer 2
    relu_gemm2<<<N_NODES / 16, 256, 0, stream>>>(h, b1, W2, sup2);
    spmm2<<<(N_EDGES * 4) / 256, 256, 0, stream>>>(esrc, edst, eval_, sup2, out);

    // softmax (+b2), in-place on out
    softmax_k<<<(N_NODES + 255) / 256, 256, 0, stream>>>(out, b2);
}

// Round 2
// 436.095 us; speedup vs baseline: 4.1520x; 4.1520x over previous
//
#include <hip/hip_runtime.h>
#include <hip/hip_bf16.h>

#define N_NODES 100000
#define N_EDGES 1600000
#define F_IN    512
#define HID     64
#define NCLS    16

#define SCAN_NB 98   // ceil(100000 / 1024)

// ---------------------------------------------------------------------------
// zero-fill (float4 grid-stride)
// ---------------------------------------------------------------------------
__global__ void zerok(float4* __restrict__ p, int n4) {
    int i = blockIdx.x * blockDim.x + threadIdx.x;
    int stride = gridDim.x * blockDim.x;
    for (; i < n4; i += stride) p[i] = make_float4(0.f, 0.f, 0.f, 0.f);
}

// ---------------------------------------------------------------------------
// CSR build step 1: histogram of edge_dst into cnt[]
// ---------------------------------------------------------------------------
__global__ __launch_bounds__(256) void histk(const int* __restrict__ edst,
                                             int* __restrict__ cnt) {
    int e = blockIdx.x * 256 + threadIdx.x;
    if (e < N_EDGES) atomicAdd(&cnt[edst[e]], 1);
}

// ---------------------------------------------------------------------------
// CSR build step 2a: per-block sums (1024 elems / block)
// ---------------------------------------------------------------------------
__global__ __launch_bounds__(256) void scan_bsum(const int* __restrict__ cnt,
                                                 int* __restrict__ bsums) {
    __shared__ int sc[256];
    int t = threadIdx.x;
    int i0 = blockIdx.x * 1024 + t * 4;
    int s = 0;
    #pragma unroll
    for (int j = 0; j < 4; j++) {
        int i = i0 + j;
        if (i < N_NODES) s += cnt[i];
    }
    sc[t] = s;
    __syncthreads();
    #pragma unroll
    for (int d = 1; d < 256; d <<= 1) {
        int v = (t >= d) ? sc[t - d] : 0;
        __syncthreads();
        sc[t] += v;
        __syncthreads();
    }
    if (t == 255) bsums[blockIdx.x] = sc[255];
}

// ---------------------------------------------------------------------------
// CSR build step 2b: exclusive scan of the 98 block sums (single block)
// ---------------------------------------------------------------------------
__global__ __launch_bounds__(128) void scan_top(const int* __restrict__ bsums,
                                                int* __restrict__ bbase,
                                                int* __restrict__ off) {
    __shared__ int sc[128];
    int t = threadIdx.x;
    int v0 = (t < SCAN_NB) ? bsums[t] : 0;
    sc[t] = v0;
    __syncthreads();
    #pragma unroll
    for (int d = 1; d < 128; d <<= 1) {
        int v = (t >= d) ? sc[t - d] : 0;
        __syncthreads();
        sc[t] += v;
        __syncthreads();
    }
    bbase[t] = sc[t] - v0;            // exclusive
    if (t == 0) off[N_NODES] = N_EDGES;
}

// ---------------------------------------------------------------------------
// CSR build step 2c: full exclusive scan -> off[], and init cursor[] = off[]
// ---------------------------------------------------------------------------
__global__ __launch_bounds__(256) void scan_final(const int* __restrict__ cnt,
                                                  const int* __restrict__ bbase,
                                                  int* __restrict__ off,
                                                  int* __restrict__ cur) {
    __shared__ int sc[256];
    int t = threadIdx.x;
    int i0 = blockIdx.x * 1024 + t * 4;
    int c[4];
    int s = 0;
    #pragma unroll
    for (int j = 0; j < 4; j++) {
        int i = i0 + j;
        c[j] = (i < N_NODES) ? cnt[i] : 0;
        s += c[j];
    }
    int tsum = s;
    sc[t] = tsum;
    __syncthreads();
    #pragma unroll
    for (int d = 1; d < 256; d <<= 1) {
        int v = (t >= d) ? sc[t - d] : 0;
        __syncthreads();
        sc[t] += v;
        __syncthreads();
    }
    int base = bbase[blockIdx.x] + sc[t] - tsum;   // exclusive prefix for this thread
    #pragma unroll
    for (int j = 0; j < 4; j++) {
        int i = i0 + j;
        if (i < N_NODES) { off[i] = base; cur[i] = base; }
        base += c[j];
    }
}

// ---------------------------------------------------------------------------
// CSR build step 3: scatter edges into dst-sorted order
// ---------------------------------------------------------------------------
__global__ __launch_bounds__(256) void scatterk(const int* __restrict__ esrc,
                                                const int* __restrict__ edst,
                                                const float* __restrict__ eval_,
                                                int* __restrict__ cur,
                                                int* __restrict__ ssrc,
                                                float* __restrict__ sval) {
    int e = blockIdx.x * 256 + threadIdx.x;
    if (e >= N_EDGES) return;
    int d = edst[e];
    int pos = atomicAdd(&cur[d], 1);
    ssrc[pos] = esrc[e];
    sval[pos] = eval_[e];
}

// ---------------------------------------------------------------------------
// GEMM1: support = x @ W1   [N,512] @ [512,64] -> [N,64], fp32 vector ALU
// ---------------------------------------------------------------------------
__global__ __launch_bounds__(256) void gemm1(const float* __restrict__ x,
                                             const float* __restrict__ W1,
                                             float* __restrict__ support) {
    __shared__ float xs[32][68];
    __shared__ float ws[32][64];

    const int tid  = threadIdx.x;
    const int tx   = tid & 15;
    const int ty   = tid >> 4;
    const int row0 = blockIdx.x * 64;

    float acc[4][4] = {};

    for (int kb = 0; kb < F_IN; kb += 32) {
        {
            const float4* wsrc = (const float4*)(W1 + kb * 64);
            float4* wdst = (float4*)(&ws[0][0]);
            wdst[tid]       = wsrc[tid];
            wdst[tid + 256] = wsrc[tid + 256];
        }
        #pragma unroll
        for (int li = 0; li < 2; li++) {
            int l   = tid + li * 256;
            int row = l >> 3;
            int kk  = (l & 7) * 4;
            float4 v = make_float4(0.f, 0.f, 0.f, 0.f);
            if (row0 + row < N_NODES)
                v = *(const float4*)(x + (long)(row0 + row) * F_IN + kb + kk);
            xs[kk + 0][row] = v.x;
            xs[kk + 1][row] = v.y;
            xs[kk + 2][row] = v.z;
            xs[kk + 3][row] = v.w;
        }
        __syncthreads();

        #pragma unroll
        for (int k = 0; k < 32; k++) {
            float4 xv = *(const float4*)&xs[k][ty * 4];
            float4 wv = *(const float4*)&ws[k][tx * 4];
            acc[0][0] += xv.x * wv.x; acc[0][1] += xv.x * wv.y;
            acc[0][2] += xv.x * wv.z; acc[0][3] += xv.x * wv.w;
            acc[1][0] += xv.y * wv.x; acc[1][1] += xv.y * wv.y;
            acc[1][2] += xv.y * wv.z; acc[1][3] += xv.y * wv.w;
            acc[2][0] += xv.z * wv.x; acc[2][1] += xv.z * wv.y;
            acc[2][2] += xv.z * wv.z; acc[2][3] += xv.z * wv.w;
            acc[3][0] += xv.w * wv.x; acc[3][1] += xv.w * wv.y;
            acc[3][2] += xv.w * wv.z; acc[3][3] += xv.w * wv.w;
        }
        __syncthreads();
    }

    #pragma unroll
    for (int r = 0; r < 4; r++) {
        int row = row0 + ty * 4 + r;
        if (row < N_NODES) {
            float4 o = make_float4(acc[r][0], acc[r][1], acc[r][2], acc[r][3]);
            *(float4*)(support + (long)row * HID + tx * 4) = o;
        }
    }
}

// ---------------------------------------------------------------------------
// SPMM1 (CSR): h[n] = relu( sum_e val*sup[src] + b1 ).  One wave per node,
// 1 float/lane (D=64). Coalesced 256B row gathers, zero atomics.
// ---------------------------------------------------------------------------
__global__ __launch_bounds__(256) void spmm1_csr(const int* __restrict__ off,
                                                 const int* __restrict__ ssrc,
                                                 const float* __restrict__ sval,
                                                 const float* __restrict__ sup,
                                                 const float* __restrict__ b1,
                                                 float* __restrict__ h) {
    int tid  = threadIdx.x;
    int lane = tid & 63;
    int n    = blockIdx.x * 4 + (tid >> 6);
    if (n >= N_NODES) return;

    int e0 = off[n];
    int e1 = off[n + 1];
    float acc = 0.f;
    int e = e0;
    for (; e + 1 < e1; e += 2) {
        int   s0 = ssrc[e],     s1 = ssrc[e + 1];
        float v0 = sval[e],     v1 = sval[e + 1];
        float g0 = sup[(long)s0 * HID + lane];
        float g1 = sup[(long)s1 * HID + lane];
        acc += v0 * g0 + v1 * g1;
    }
    if (e < e1) {
        int   s0 = ssrc[e];
        float v0 = sval[e];
        acc += v0 * sup[(long)s0 * HID + lane];
    }
    h[(long)n * HID + lane] = fmaxf(acc + b1[lane], 0.f);
}

// ---------------------------------------------------------------------------
// GEMM2: sup2 = h @ W2  [N,64]@[64,16]. 16 threads per node.
// ---------------------------------------------------------------------------
__global__ __launch_bounds__(256) void gemm2(const float* __restrict__ h,
                                             const float* __restrict__ W2,
                                             float* __restrict__ sup2) {
    __shared__ float w2s[HID * NCLS];
    int tid = threadIdx.x;
    for (int i = tid; i < HID * NCLS; i += 256) w2s[i] = W2[i];
    __syncthreads();

    int node = blockIdx.x * 16 + (tid >> 4);
    int c    = tid & 15;
    if (node >= N_NODES) return;
    const float* hr = h + (long)node * HID;
    float acc = 0.f;
    #pragma unroll
    for (int k = 0; k < HID; k++) {
        acc += hr[k] * w2s[k * NCLS + c];
    }
    sup2[(long)node * NCLS + c] = acc;
}

// ---------------------------------------------------------------------------
// SPMM2 (CSR) fused with +b2 and softmax. 16 lanes per node.
// ---------------------------------------------------------------------------
__global__ __launch_bounds__(256) void spmm2_softmax(const int* __restrict__ off,
                                                     const int* __restrict__ ssrc,
                                                     const float* __restrict__ sval,
                                                     const float* __restrict__ sup2,
                                                     const float* __restrict__ b2,
                                                     float* __restrict__ out) {
    int tid = threadIdx.x;
    int n   = blockIdx.x * 16 + (tid >> 4);
    int c   = tid & 15;
    if (n >= N_NODES) return;

    int e0 = off[n];
    int e1 = off[n + 1];
    float acc = 0.f;
    int e = e0;
    for (; e + 1 < e1; e += 2) {
        int   s0 = ssrc[e],  s1 = ssrc[e + 1];
        float v0 = sval[e],  v1 = sval[e + 1];
        acc += v0 * sup2[(long)s0 * NCLS + c] + v1 * sup2[(long)s1 * NCLS + c];
    }
    if (e < e1) {
        acc += sval[e] * sup2[(long)ssrc[e] * NCLS + c];
    }

    float l = acc + b2[c];
    float m = l;
    #pragma unroll
    for (int mask = 1; mask < 16; mask <<= 1)
        m = fmaxf(m, __shfl_xor(m, mask, 16));
    float p = expf(l - m);
    float s = p;
    #pragma unroll
    for (int mask = 1; mask < 16; mask <<= 1)
        s += __shfl_xor(s, mask, 16);
    out[(long)n * NCLS + c] = p / s;
}

// ---------------------------------------------------------------------------
extern "C" void kernel_launch(void* const* d_in, const int* in_sizes, int n_in,
                              void* d_out, int out_size, void* d_ws, size_t ws_size,
                              hipStream_t stream) {
    const float* x     = (const float*)d_in[0];
    const int*   esrc  = (const int*)  d_in[1];
    const int*   edst  = (const int*)  d_in[2];
    const float* eval_ = (const float*)d_in[3];
    const float* W1    = (const float*)d_in[4];
    const float* b1    = (const float*)d_in[5];
    const float* W2    = (const float*)d_in[6];
    const float* b2    = (const float*)d_in[7];
    float* out = (float*)d_out;

    // workspace layout (floats/ints, 4B units)
    float* sup1  = (float*)d_ws;                        // 6,400,000 f
    float* h     = sup1 + (long)N_NODES * HID;          // 6,400,000 f
    float* sup2  = h    + (long)N_NODES * HID;          // 1,600,000 f
    float* sval  = sup2 + (long)N_NODES * NCLS;         // 1,600,000 f
    int*   ssrc  = (int*)(sval + N_EDGES);              // 1,600,000 i
    int*   off   = ssrc + N_EDGES;                      // 100,004 i
    int*   cur   = off + 100004;                        // 100,000 i
    int*   bsums = cur + N_NODES;                       // 128 i
    int*   bbase = bsums + 128;                         // 128 i
    // total ~ 72 MB

    // --- CSR build (deterministic work each call) ---
    zerok<<<128, 256, 0, stream>>>((float4*)cur, N_NODES / 4);      // counts
    histk<<<(N_EDGES + 255) / 256, 256, 0, stream>>>(edst, cur);
    scan_bsum<<<SCAN_NB, 256, 0, stream>>>(cur, bsums);
    scan_top<<<1, 128, 0, stream>>>(bsums, bbase, off);
    scan_final<<<SCAN_NB, 256, 0, stream>>>(cur, bbase, off, cur);
    scatterk<<<(N_EDGES + 255) / 256, 256, 0, stream>>>(esrc, edst, eval_, cur, ssrc, sval);

    // --- layer 1 ---
    gemm1<<<(N_NODES + 63) / 64, 256, 0, stream>>>(x, W1, sup1);
    spmm1_csr<<<(N_NODES + 3) / 4, 256, 0, stream>>>(off, ssrc, sval, sup1, b1, h);

    // --- layer 2 + softmax ---
    gemm2<<<(N_NODES + 15) / 16, 256, 0, stream>>>(h, W2, sup2);
    spmm2_softmax<<<(N_NODES + 15) / 16, 256, 0, stream>>>(off, ssrc, sval, sup2, b2, out);
}

// Round 3
// 409.558 us; speedup vs baseline: 4.4210x; 1.0648x over previous
//
#include <hip/hip_runtime.h>
#include <hip/hip_bf16.h>

#define N_NODES 100000
#define N_EDGES 1600000
#define F_IN    512
#define HID     64
#define NCLS    16

#define SCAN_NB 98   // ceil(100000 / 1024)

typedef __attribute__((ext_vector_type(8))) short short8;
typedef __attribute__((ext_vector_type(4))) float f32x4;

// ---------------------------------------------------------------------------
// zero-fill (float4 grid-stride)
// ---------------------------------------------------------------------------
__global__ void zerok(float4* __restrict__ p, int n4) {
    int i = blockIdx.x * blockDim.x + threadIdx.x;
    int stride = gridDim.x * blockDim.x;
    for (; i < n4; i += stride) p[i] = make_float4(0.f, 0.f, 0.f, 0.f);
}

// ---------------------------------------------------------------------------
// CSR build step 1: histogram of edge_dst into cnt[]
// ---------------------------------------------------------------------------
__global__ __launch_bounds__(256) void histk(const int* __restrict__ edst,
                                             int* __restrict__ cnt) {
    int e = blockIdx.x * 256 + threadIdx.x;
    if (e < N_EDGES) atomicAdd(&cnt[edst[e]], 1);
}

// ---------------------------------------------------------------------------
// CSR build step 2a: per-block sums (1024 elems / block)
// ---------------------------------------------------------------------------
__global__ __launch_bounds__(256) void scan_bsum(const int* __restrict__ cnt,
                                                 int* __restrict__ bsums) {
    __shared__ int sc[256];
    int t = threadIdx.x;
    int i0 = blockIdx.x * 1024 + t * 4;
    int s = 0;
    #pragma unroll
    for (int j = 0; j < 4; j++) {
        int i = i0 + j;
        if (i < N_NODES) s += cnt[i];
    }
    sc[t] = s;
    __syncthreads();
    #pragma unroll
    for (int d = 1; d < 256; d <<= 1) {
        int v = (t >= d) ? sc[t - d] : 0;
        __syncthreads();
        sc[t] += v;
        __syncthreads();
    }
    if (t == 255) bsums[blockIdx.x] = sc[255];
}

// ---------------------------------------------------------------------------
// CSR build step 2b: exclusive scan of the 98 block sums (single block)
// ---------------------------------------------------------------------------
__global__ __launch_bounds__(128) void scan_top(const int* __restrict__ bsums,
                                                int* __restrict__ bbase,
                                                int* __restrict__ off) {
    __shared__ int sc[128];
    int t = threadIdx.x;
    int v0 = (t < SCAN_NB) ? bsums[t] : 0;
    sc[t] = v0;
    __syncthreads();
    #pragma unroll
    for (int d = 1; d < 128; d <<= 1) {
        int v = (t >= d) ? sc[t - d] : 0;
        __syncthreads();
        sc[t] += v;
        __syncthreads();
    }
    bbase[t] = sc[t] - v0;            // exclusive
    if (t == 0) off[N_NODES] = N_EDGES;
}

// ---------------------------------------------------------------------------
// CSR build step 2c: full exclusive scan -> off[], and init cursor[] = off[]
// ---------------------------------------------------------------------------
__global__ __launch_bounds__(256) void scan_final(const int* __restrict__ cnt,
                                                  const int* __restrict__ bbase,
                                                  int* __restrict__ off,
                                                  int* __restrict__ cur) {
    __shared__ int sc[256];
    int t = threadIdx.x;
    int i0 = blockIdx.x * 1024 + t * 4;
    int c[4];
    int s = 0;
    #pragma unroll
    for (int j = 0; j < 4; j++) {
        int i = i0 + j;
        c[j] = (i < N_NODES) ? cnt[i] : 0;
        s += c[j];
    }
    int tsum = s;
    sc[t] = tsum;
    __syncthreads();
    #pragma unroll
    for (int d = 1; d < 256; d <<= 1) {
        int v = (t >= d) ? sc[t - d] : 0;
        __syncthreads();
        sc[t] += v;
        __syncthreads();
    }
    int base = bbase[blockIdx.x] + sc[t] - tsum;
    #pragma unroll
    for (int j = 0; j < 4; j++) {
        int i = i0 + j;
        if (i < N_NODES) { off[i] = base; cur[i] = base; }
        base += c[j];
    }
}

// ---------------------------------------------------------------------------
// CSR build step 3: scatter edges into dst-sorted order
// ---------------------------------------------------------------------------
__global__ __launch_bounds__(256) void scatterk(const int* __restrict__ esrc,
                                                const int* __restrict__ edst,
                                                const float* __restrict__ eval_,
                                                int* __restrict__ cur,
                                                int* __restrict__ ssrc,
                                                float* __restrict__ sval) {
    int e = blockIdx.x * 256 + threadIdx.x;
    if (e >= N_EDGES) return;
    int d = edst[e];
    int pos = atomicAdd(&cur[d], 1);
    ssrc[pos] = esrc[e];
    sval[pos] = eval_[e];
}

// ---------------------------------------------------------------------------
// split fp32 -> bf16 hi + bf16 lo (truncation; residual ~2^-16 relative)
// ---------------------------------------------------------------------------
__device__ inline void split_bf16(float a, unsigned short& hi, unsigned short& lo) {
    unsigned u = __float_as_uint(a);
    hi = (unsigned short)(u >> 16);
    float hif = __uint_as_float(((unsigned)hi) << 16);
    float lof = a - hif;
    lo = (unsigned short)(__float_as_uint(lof) >> 16);
}

// ---------------------------------------------------------------------------
// prep: W1 [512][64] fp32 -> Wg fragment-native bf16 hi/lo layout
// Wg[nt(4)][kc(16)][h(2)][lane(64)][j(8)] ushort:
//   lane l of a wave loads 16B at ((nt*16+kc)*2+h)*1024B + l*16B  (coalesced)
//   holding  n = nt*16 + (l&15), k = kc*32 + (l>>4)*8 + j
// ---------------------------------------------------------------------------
__global__ __launch_bounds__(256) void prep_w1(const float* __restrict__ W1,
                                               unsigned short* __restrict__ Wg) {
    int idx = blockIdx.x * 256 + threadIdx.x;   // 0 .. 32767
    if (idx >= F_IN * HID) return;
    int k = idx >> 6, n = idx & 63;
    unsigned short hi, lo;
    split_bf16(W1[idx], hi, lo);
    int nt = n >> 4, kc = k >> 5;
    int l  = ((k >> 3) & 3) * 16 + (n & 15);
    int j  = k & 7;
    long base = ((((long)nt * 16 + kc) * 2) * 64 + l) * 8 + j;
    Wg[base]       = hi;
    Wg[base + 512] = lo;   // h-dim stride = 64*8
}

// ---------------------------------------------------------------------------
// GEMM1 via split-bf16 MFMA: support = x @ W1  [N,512]@[512,64] -> [N,64]
// block = 256 thr = 4 waves; tile 64 rows; wave w owns rows w*16..+15, all 64
// cols (4 n-tiles of 16). K chunked by 64, x staged hi/lo in LDS (pad 72).
// B-fragments load directly from Wg (L2-resident, coalesced).
// 3 MFMA per (ntile,kstep): hi*hi + hi*lo + lo*hi  ~ fp32 accuracy.
// ---------------------------------------------------------------------------
__global__ __launch_bounds__(256) void gemm1_mfma(const float* __restrict__ x,
                                                  const unsigned short* __restrict__ Wg,
                                                  float* __restrict__ support) {
    __shared__ unsigned short Ahi[64 * 72];
    __shared__ unsigned short Alo[64 * 72];

    const int tid  = threadIdx.x;
    const int l    = tid & 63;
    const int w    = tid >> 6;
    const int lr   = l & 15;
    const int lg   = l >> 4;
    const int row0 = blockIdx.x * 64;

    f32x4 acc[4] = {};

    for (int kb = 0; kb < F_IN; kb += 64) {
        // --- stage x chunk: 64 rows x 64 k, fp32 -> bf16 hi/lo ---
        #pragma unroll
        for (int j = 0; j < 4; j++) {
            int f   = tid + j * 256;       // 0..1023 float4 slots
            int row = f >> 4;
            int kq  = f & 15;
            float4 v = make_float4(0.f, 0.f, 0.f, 0.f);
            if (row0 + row < N_NODES)
                v = *(const float4*)(x + (long)(row0 + row) * F_IN + kb + kq * 4);
            unsigned short h0, l0, h1, l1, h2, l2, h3, l3;
            split_bf16(v.x, h0, l0);
            split_bf16(v.y, h1, l1);
            split_bf16(v.z, h2, l2);
            split_bf16(v.w, h3, l3);
            *(ushort4*)&Ahi[row * 72 + kq * 4] = make_ushort4(h0, h1, h2, h3);
            *(ushort4*)&Alo[row * 72 + kq * 4] = make_ushort4(l0, l1, l2, l3);
        }
        __syncthreads();

        #pragma unroll
        for (int ks = 0; ks < 2; ks++) {
            int kc = (kb >> 5) + ks;
            short8 ah = *(const short8*)&Ahi[(w * 16 + lr) * 72 + ks * 32 + lg * 8];
            short8 al = *(const short8*)&Alo[(w * 16 + lr) * 72 + ks * 32 + lg * 8];
            #pragma unroll
            for (int nt = 0; nt < 4; nt++) {
                long bo = ((((long)nt * 16 + kc) * 2) * 64 + l) * 8;
                short8 bh = *(const short8*)(Wg + bo);
                short8 bl = *(const short8*)(Wg + bo + 512);
                acc[nt] = __builtin_amdgcn_mfma_f32_16x16x32_bf16(ah, bh, acc[nt], 0, 0, 0);
                acc[nt] = __builtin_amdgcn_mfma_f32_16x16x32_bf16(ah, bl, acc[nt], 0, 0, 0);
                acc[nt] = __builtin_amdgcn_mfma_f32_16x16x32_bf16(al, bh, acc[nt], 0, 0, 0);
            }
        }
        __syncthreads();
    }

    // epilogue: C/D layout col = lane&15, row = (lane>>4)*4 + reg
    #pragma unroll
    for (int nt = 0; nt < 4; nt++) {
        #pragma unroll
        for (int r = 0; r < 4; r++) {
            int row = row0 + w * 16 + lg * 4 + r;
            if (row < N_NODES)
                support[(long)row * HID + nt * 16 + lr] = acc[nt][r];
        }
    }
}

// ---------------------------------------------------------------------------
// SPMM1 (CSR): h[n] = relu( sum_e val*sup[src] + b1 ).  One wave per node.
// ---------------------------------------------------------------------------
__global__ __launch_bounds__(256) void spmm1_csr(const int* __restrict__ off,
                                                 const int* __restrict__ ssrc,
                                                 const float* __restrict__ sval,
                                                 const float* __restrict__ sup,
                                                 const float* __restrict__ b1,
                                                 float* __restrict__ h) {
    int tid  = threadIdx.x;
    int lane = tid & 63;
    int n    = blockIdx.x * 4 + (tid >> 6);
    if (n >= N_NODES) return;

    int e0 = off[n];
    int e1 = off[n + 1];
    float acc = 0.f;
    int e = e0;
    for (; e + 1 < e1; e += 2) {
        int   s0 = ssrc[e],     s1 = ssrc[e + 1];
        float v0 = sval[e],     v1 = sval[e + 1];
        float g0 = sup[(long)s0 * HID + lane];
        float g1 = sup[(long)s1 * HID + lane];
        acc += v0 * g0 + v1 * g1;
    }
    if (e < e1) {
        acc += sval[e] * sup[(long)ssrc[e] * HID + lane];
    }
    h[(long)n * HID + lane] = fmaxf(acc + b1[lane], 0.f);
}

// ---------------------------------------------------------------------------
// GEMM2: sup2 = h @ W2  [N,64]@[64,16]. 16 threads per node.
// ---------------------------------------------------------------------------
__global__ __launch_bounds__(256) void gemm2(const float* __restrict__ h,
                                             const float* __restrict__ W2,
                                             float* __restrict__ sup2) {
    __shared__ float w2s[HID * NCLS];
    int tid = threadIdx.x;
    for (int i = tid; i < HID * NCLS; i += 256) w2s[i] = W2[i];
    __syncthreads();

    int node = blockIdx.x * 16 + (tid >> 4);
    int c    = tid & 15;
    if (node >= N_NODES) return;
    const float* hr = h + (long)node * HID;
    float acc = 0.f;
    #pragma unroll
    for (int k = 0; k < HID; k++) {
        acc += hr[k] * w2s[k * NCLS + c];
    }
    sup2[(long)node * NCLS + c] = acc;
}

// ---------------------------------------------------------------------------
// SPMM2 (CSR) fused with +b2 and softmax. 16 lanes per node.
// ---------------------------------------------------------------------------
__global__ __launch_bounds__(256) void spmm2_softmax(const int* __restrict__ off,
                                                     const int* __restrict__ ssrc,
                                                     const float* __restrict__ sval,
                                                     const float* __restrict__ sup2,
                                                     const float* __restrict__ b2,
                                                     float* __restrict__ out) {
    int tid = threadIdx.x;
    int n   = blockIdx.x * 16 + (tid >> 4);
    int c   = tid & 15;
    if (n >= N_NODES) return;

    int e0 = off[n];
    int e1 = off[n + 1];
    float acc = 0.f;
    int e = e0;
    for (; e + 1 < e1; e += 2) {
        int   s0 = ssrc[e],  s1 = ssrc[e + 1];
        float v0 = sval[e],  v1 = sval[e + 1];
        acc += v0 * sup2[(long)s0 * NCLS + c] + v1 * sup2[(long)s1 * NCLS + c];
    }
    if (e < e1) {
        acc += sval[e] * sup2[(long)ssrc[e] * NCLS + c];
    }

    float l = acc + b2[c];
    float m = l;
    #pragma unroll
    for (int mask = 1; mask < 16; mask <<= 1)
        m = fmaxf(m, __shfl_xor(m, mask, 16));
    float p = expf(l - m);
    float s = p;
    #pragma unroll
    for (int mask = 1; mask < 16; mask <<= 1)
        s += __shfl_xor(s, mask, 16);
    out[(long)n * NCLS + c] = p / s;
}

// ---------------------------------------------------------------------------
extern "C" void kernel_launch(void* const* d_in, const int* in_sizes, int n_in,
                              void* d_out, int out_size, void* d_ws, size_t ws_size,
                              hipStream_t stream) {
    const float* x     = (const float*)d_in[0];
    const int*   esrc  = (const int*)  d_in[1];
    const int*   edst  = (const int*)  d_in[2];
    const float* eval_ = (const float*)d_in[3];
    const float* W1    = (const float*)d_in[4];
    const float* b1    = (const float*)d_in[5];
    const float* W2    = (const float*)d_in[6];
    const float* b2    = (const float*)d_in[7];
    float* out = (float*)d_out;

    // workspace layout (4B units; all segment sizes are multiples of 4 ->
    // every base stays 16B-aligned)
    float* sup1  = (float*)d_ws;                        // 6,400,000 f
    float* h     = sup1 + (long)N_NODES * HID;          // 6,400,000 f
    float* sup2  = h    + (long)N_NODES * HID;          // 1,600,000 f
    float* sval  = sup2 + (long)N_NODES * NCLS;         // 1,600,000 f
    int*   ssrc  = (int*)(sval + N_EDGES);              // 1,600,000 i
    int*   off   = ssrc + N_EDGES;                      // 100,004 i
    int*   cur   = off + 100004;                        // 100,000 i
    int*   bsums = cur + N_NODES;                       // 128 i
    int*   bbase = bsums + 128;                         // 128 i
    unsigned short* Wg = (unsigned short*)(bbase + 128);// 65,536 us (128 KB)

    // --- CSR build (deterministic work each call) ---
    zerok<<<128, 256, 0, stream>>>((float4*)cur, N_NODES / 4);
    histk<<<(N_EDGES + 255) / 256, 256, 0, stream>>>(edst, cur);
    scan_bsum<<<SCAN_NB, 256, 0, stream>>>(cur, bsums);
    scan_top<<<1, 128, 0, stream>>>(bsums, bbase, off);
    scan_final<<<SCAN_NB, 256, 0, stream>>>(cur, bbase, off, cur);
    scatterk<<<(N_EDGES + 255) / 256, 256, 0, stream>>>(esrc, edst, eval_, cur, ssrc, sval);

    // --- W1 fragment prep + layer 1 ---
    prep_w1<<<(F_IN * HID + 255) / 256, 256, 0, stream>>>(W1, Wg);
    gemm1_mfma<<<(N_NODES + 63) / 64, 256, 0, stream>>>(x, Wg, sup1);
    spmm1_csr<<<(N_NODES + 3) / 4, 256, 0, stream>>>(off, ssrc, sval, sup1, b1, h);

    // --- layer 2 + softmax ---
    gemm2<<<(N_NODES + 15) / 16, 256, 0, stream>>>(h, W2, sup2);
    spmm2_softmax<<<(N_NODES + 15) / 16, 256, 0, stream>>>(off, ssrc, sval, sup2, b2, out);
}

// Round 5
// 400.748 us; speedup vs baseline: 4.5182x; 1.0220x over previous
//
#include <hip/hip_runtime.h>
#include <hip/hip_bf16.h>

#define N_NODES 100000
#define N_EDGES 1600000
#define F_IN    512
#define HID     64
#define NCLS    16

#define SCAN_NB 98   // ceil(100000 / 1024)
#define BM      128  // gemm1 row tile

typedef __attribute__((ext_vector_type(8))) short short8;
typedef __attribute__((ext_vector_type(4))) float f32x4;
typedef unsigned int u32;
typedef unsigned short u16;

// ---------------------------------------------------------------------------
// async global->LDS 16B (wave-uniform LDS base + lane*16 dest semantics)
// ---------------------------------------------------------------------------
__device__ inline void gload_lds16(const float* g, float* l) {
    __builtin_amdgcn_global_load_lds(
        (const __attribute__((address_space(1))) u32*)g,
        (__attribute__((address_space(3))) u32*)l, 16, 0, 0);
}

// ---------------------------------------------------------------------------
// zero-fill (float4 grid-stride)
// ---------------------------------------------------------------------------
__global__ void zerok(float4* __restrict__ p, int n4) {
    int i = blockIdx.x * blockDim.x + threadIdx.x;
    int stride = gridDim.x * blockDim.x;
    for (; i < n4; i += stride) p[i] = make_float4(0.f, 0.f, 0.f, 0.f);
}

// ---------------------------------------------------------------------------
// CSR build step 1: histogram of edge_dst
// ---------------------------------------------------------------------------
__global__ __launch_bounds__(256) void histk(const int* __restrict__ edst,
                                             int* __restrict__ cnt) {
    int e = blockIdx.x * 256 + threadIdx.x;
    if (e < N_EDGES) atomicAdd(&cnt[edst[e]], 1);
}

// ---------------------------------------------------------------------------
// CSR build step 2a: per-block sums (1024 elems / block)
// ---------------------------------------------------------------------------
__global__ __launch_bounds__(256) void scan_bsum(const int* __restrict__ cnt,
                                                 int* __restrict__ bsums) {
    __shared__ int sc[256];
    int t = threadIdx.x;
    int i0 = blockIdx.x * 1024 + t * 4;
    int s = 0;
    #pragma unroll
    for (int j = 0; j < 4; j++) {
        int i = i0 + j;
        if (i < N_NODES) s += cnt[i];
    }
    sc[t] = s;
    __syncthreads();
    #pragma unroll
    for (int d = 1; d < 256; d <<= 1) {
        int v = (t >= d) ? sc[t - d] : 0;
        __syncthreads();
        sc[t] += v;
        __syncthreads();
    }
    if (t == 255) bsums[blockIdx.x] = sc[255];
}

// ---------------------------------------------------------------------------
// CSR build step 2b: exclusive scan of the block sums (single block)
// ---------------------------------------------------------------------------
__global__ __launch_bounds__(128) void scan_top(const int* __restrict__ bsums,
                                                int* __restrict__ bbase,
                                                int* __restrict__ off) {
    __shared__ int sc[128];
    int t = threadIdx.x;
    int v0 = (t < SCAN_NB) ? bsums[t] : 0;
    sc[t] = v0;
    __syncthreads();
    #pragma unroll
    for (int d = 1; d < 128; d <<= 1) {
        int v = (t >= d) ? sc[t - d] : 0;
        __syncthreads();
        sc[t] += v;
        __syncthreads();
    }
    bbase[t] = sc[t] - v0;
    if (t == 0) off[N_NODES] = N_EDGES;
}

// ---------------------------------------------------------------------------
// CSR build step 2c: full exclusive scan -> off[], cursor init
// ---------------------------------------------------------------------------
__global__ __launch_bounds__(256) void scan_final(const int* __restrict__ cnt,
                                                  const int* __restrict__ bbase,
                                                  int* __restrict__ off,
                                                  int* __restrict__ cur) {
    __shared__ int sc[256];
    int t = threadIdx.x;
    int i0 = blockIdx.x * 1024 + t * 4;
    int c[4];
    int s = 0;
    #pragma unroll
    for (int j = 0; j < 4; j++) {
        int i = i0 + j;
        c[j] = (i < N_NODES) ? cnt[i] : 0;
        s += c[j];
    }
    int tsum = s;
    sc[t] = tsum;
    __syncthreads();
    #pragma unroll
    for (int d = 1; d < 256; d <<= 1) {
        int v = (t >= d) ? sc[t - d] : 0;
        __syncthreads();
        sc[t] += v;
        __syncthreads();
    }
    int base = bbase[blockIdx.x] + sc[t] - tsum;
    #pragma unroll
    for (int j = 0; j < 4; j++) {
        int i = i0 + j;
        if (i < N_NODES) { off[i] = base; cur[i] = base; }
        base += c[j];
    }
}

// ---------------------------------------------------------------------------
// CSR build step 3: scatter edges, packed (src, val) as int2 (one 8B store)
// ---------------------------------------------------------------------------
__global__ __launch_bounds__(256) void scatterk(const int* __restrict__ esrc,
                                                const int* __restrict__ edst,
                                                const float* __restrict__ eval_,
                                                int* __restrict__ cur,
                                                int2* __restrict__ epk) {
    int e = blockIdx.x * 256 + threadIdx.x;
    if (e >= N_EDGES) return;
    int d = edst[e];
    int pos = atomicAdd(&cur[d], 1);
    epk[pos] = make_int2(esrc[e], __float_as_int(eval_[e]));
}

// ---------------------------------------------------------------------------
// split fp32 -> bf16 hi + bf16 lo (truncation; residual ~2^-16 relative)
// ---------------------------------------------------------------------------
__device__ inline void split_bf16(float a, unsigned short& hi, unsigned short& lo) {
    unsigned u = __float_as_uint(a);
    hi = (unsigned short)(u >> 16);
    float hif = __uint_as_float(((unsigned)hi) << 16);
    float lof = a - hif;
    lo = (unsigned short)(__float_as_uint(lof) >> 16);
}

// split 8 fp32 (two f32x4) into hi/lo short8 fragments
__device__ inline void split8(f32x4 a, f32x4 b, short8& hi, short8& lo) {
    #pragma unroll
    for (int i = 0; i < 4; i++) {
        u16 h, l;
        split_bf16(a[i], h, l);
        hi[i] = (short)h; lo[i] = (short)l;
    }
    #pragma unroll
    for (int i = 0; i < 4; i++) {
        u16 h, l;
        split_bf16(b[i], h, l);
        hi[4 + i] = (short)h; lo[4 + i] = (short)l;
    }
}

// ---------------------------------------------------------------------------
// prep: W1 [512][64] fp32 -> Wg fragment-native bf16 hi/lo layout
// Wg[nt(4)][kc(16)][h(2)][lane(64)][j(8)] ushort:
//   lane l loads 16B holding n = nt*16 + (l&15), k = kc*32 + (l>>4)*8 + j
// ---------------------------------------------------------------------------
__global__ __launch_bounds__(256) void prep_w1(const float* __restrict__ W1,
                                               unsigned short* __restrict__ Wg) {
    int idx = blockIdx.x * 256 + threadIdx.x;   // 0 .. 32767
    if (idx >= F_IN * HID) return;
    int k = idx >> 6, n = idx & 63;
    unsigned short hi, lo;
    split_bf16(W1[idx], hi, lo);
    int nt = n >> 4, kc = k >> 5;
    int l  = ((k >> 3) & 3) * 16 + (n & 15);
    int j  = k & 7;
    long base = ((((long)nt * 16 + kc) * 2) * 64 + l) * 8 + j;
    Wg[base]       = hi;
    Wg[base + 512] = lo;
}

// ---------------------------------------------------------------------------
// GEMM1 v2 (staging coverage FIXED): support = x @ W1 via split-bf16 MFMA.
// 128-row tile needs 128*16 = 2048 16B slots -> 8 j-iters x 256 threads.
// slotbase = j*256 + w*64 (wave-uniform), slot = slotbase + lane  (bijective
// over 0..2047).  16B-chunk XOR swizzle: LDS chunk c holds global chunk
// c ^ (row&7)  (inverse applied on global src, rule #21).
// ---------------------------------------------------------------------------
__global__ __launch_bounds__(256, 2) void gemm1_mfma(const float* __restrict__ x,
                                                     const unsigned short* __restrict__ Wg,
                                                     float* __restrict__ support) {
    __shared__ float tile[BM * 64];   // 32 KB

    const int tid  = threadIdx.x;
    const int l    = tid & 63;
    const int w    = tid >> 6;
    const int lr   = l & 15;
    const int lg   = l >> 4;
    const int row0 = blockIdx.x * BM;

    f32x4 acc[2][4] = {};

    for (int kb = 0; kb < F_IN; kb += 64) {
        // --- stage: 2048 16B slots via global_load_lds ---
        #pragma unroll
        for (int j = 0; j < 8; j++) {
            int slotbase = j * 256 + w * 64;        // wave-uniform
            int slot     = slotbase + l;
            int row      = slot >> 4;
            int cl       = (slot & 15) ^ (row & 7); // inverse swizzle on src
            int rr       = row0 + row;
            if (rr > N_NODES - 1) rr = N_NODES - 1; // clamp (rows >= N discarded)
            gload_lds16(x + (long)rr * F_IN + kb + cl * 4, tile + slotbase * 4);
        }
        __syncthreads();

        #pragma unroll
        for (int ks = 0; ks < 2; ks++) {
            int kc = (kb >> 5) + ks;
            short8 ah[2], al[2];
            #pragma unroll
            for (int m = 0; m < 2; m++) {
                int r  = m * 64 + w * 16 + lr;
                int c0 = ks * 8 + lg * 2;
                f32x4 v0 = *(const f32x4*)&tile[r * 64 + ((c0 ^ (r & 7)) << 2)];
                f32x4 v1 = *(const f32x4*)&tile[r * 64 + (((c0 + 1) ^ (r & 7)) << 2)];
                split8(v0, v1, ah[m], al[m]);
            }
            #pragma unroll
            for (int nt = 0; nt < 4; nt++) {
                long bo = ((((long)nt * 16 + kc) * 2) * 64 + l) * 8;
                short8 bh = *(const short8*)(Wg + bo);
                short8 bl = *(const short8*)(Wg + bo + 512);
                #pragma unroll
                for (int m = 0; m < 2; m++) {
                    acc[m][nt] = __builtin_amdgcn_mfma_f32_16x16x32_bf16(ah[m], bh, acc[m][nt], 0, 0, 0);
                    acc[m][nt] = __builtin_amdgcn_mfma_f32_16x16x32_bf16(ah[m], bl, acc[m][nt], 0, 0, 0);
                    acc[m][nt] = __builtin_amdgcn_mfma_f32_16x16x32_bf16(al[m], bh, acc[m][nt], 0, 0, 0);
                }
            }
        }
        __syncthreads();
    }

    // epilogue: C/D layout col = lane&15, row = (lane>>4)*4 + reg
    #pragma unroll
    for (int m = 0; m < 2; m++) {
        #pragma unroll
        for (int nt = 0; nt < 4; nt++) {
            #pragma unroll
            for (int r = 0; r < 4; r++) {
                int row = row0 + m * 64 + w * 16 + lg * 4 + r;
                if (row < N_NODES)
                    support[(long)row * HID + nt * 16 + lr] = acc[m][nt][r];
            }
        }
    }
}

// ---------------------------------------------------------------------------
// SPMM1 + bias + relu + GEMM2 fused:
//   sup2[n] = relu( sum_e val*sup1[src] + b1 ) @ W2
// One wave per node: 64-lane gather-accumulate, h-row through wave-local LDS,
// 16 FMA/lane vs LDS W2, butterfly reduce, 16-lane store.
// ---------------------------------------------------------------------------
__global__ __launch_bounds__(256) void spmm1_fused(const int* __restrict__ off,
                                                   const int2* __restrict__ epk,
                                                   const float* __restrict__ sup,
                                                   const float* __restrict__ b1,
                                                   const float* __restrict__ W2,
                                                   float* __restrict__ sup2) {
    __shared__ float w2s[HID * NCLS];   // [k][c]
    __shared__ float hrow[4][HID];
    int tid = threadIdx.x;
    for (int i = tid; i < HID * NCLS; i += 256) w2s[i] = W2[i];
    __syncthreads();

    int lane = tid & 63;
    int w    = tid >> 6;
    int n    = blockIdx.x * 4 + w;      // grid exact: N_NODES % 4 == 0

    int e0 = off[n];
    int e1 = off[n + 1];
    float acc = 0.f;
    int e = e0;
    for (; e + 1 < e1; e += 2) {
        int2 p0 = epk[e], p1 = epk[e + 1];
        acc += __int_as_float(p0.y) * sup[(long)p0.x * HID + lane]
             + __int_as_float(p1.y) * sup[(long)p1.x * HID + lane];
    }
    if (e < e1) {
        int2 p = epk[e];
        acc += __int_as_float(p.y) * sup[(long)p.x * HID + lane];
    }
    float hv = fmaxf(acc + b1[lane], 0.f);

    hrow[w][lane] = hv;
    asm volatile("s_waitcnt lgkmcnt(0)" ::: "memory");   // wave-local LDS drain
    __builtin_amdgcn_sched_barrier(0);                   // rule #18 fence

    int c = lane & 15, q = lane >> 4;
    float part = 0.f;
    #pragma unroll
    for (int k0 = 0; k0 < 16; k0++) {
        int k = q * 16 + k0;
        part += hrow[w][k] * w2s[k * NCLS + c];
    }
    part += __shfl_xor(part, 16);
    part += __shfl_xor(part, 32);
    if (lane < 16) sup2[(long)n * NCLS + c] = part;
}

// ---------------------------------------------------------------------------
// SPMM2 (CSR) fused with +b2 and softmax. 16 lanes per node.
// ---------------------------------------------------------------------------
__global__ __launch_bounds__(256) void spmm2_softmax(const int* __restrict__ off,
                                                     const int2* __restrict__ epk,
                                                     const float* __restrict__ sup2,
                                                     const float* __restrict__ b2,
                                                     float* __restrict__ out) {
    int tid = threadIdx.x;
    int n   = blockIdx.x * 16 + (tid >> 4);
    int c   = tid & 15;
    if (n >= N_NODES) return;

    int e0 = off[n];
    int e1 = off[n + 1];
    float acc = 0.f;
    int e = e0;
    for (; e + 1 < e1; e += 2) {
        int2 p0 = epk[e], p1 = epk[e + 1];
        acc += __int_as_float(p0.y) * sup2[(long)p0.x * NCLS + c]
             + __int_as_float(p1.y) * sup2[(long)p1.x * NCLS + c];
    }
    if (e < e1) {
        int2 p = epk[e];
        acc += __int_as_float(p.y) * sup2[(long)p.x * NCLS + c];
    }

    float lg = acc + b2[c];
    float m = lg;
    #pragma unroll
    for (int mask = 1; mask < 16; mask <<= 1)
        m = fmaxf(m, __shfl_xor(m, mask, 16));
    float p = expf(lg - m);
    float s = p;
    #pragma unroll
    for (int mask = 1; mask < 16; mask <<= 1)
        s += __shfl_xor(s, mask, 16);
    out[(long)n * NCLS + c] = p / s;
}

// ---------------------------------------------------------------------------
extern "C" void kernel_launch(void* const* d_in, const int* in_sizes, int n_in,
                              void* d_out, int out_size, void* d_ws, size_t ws_size,
                              hipStream_t stream) {
    const float* x     = (const float*)d_in[0];
    const int*   esrc  = (const int*)  d_in[1];
    const int*   edst  = (const int*)  d_in[2];
    const float* eval_ = (const float*)d_in[3];
    const float* W1    = (const float*)d_in[4];
    const float* b1    = (const float*)d_in[5];
    const float* W2    = (const float*)d_in[6];
    const float* b2    = (const float*)d_in[7];
    float* out = (float*)d_out;

    // workspace layout (4B units; every base 16B-aligned)
    float* sup1  = (float*)d_ws;                        // 6,400,000 f
    float* sup2  = sup1 + (long)N_NODES * HID;          // 1,600,000 f
    int2*  epk   = (int2*)(sup2 + (long)N_NODES * NCLS);// 1,600,000 int2
    int*   off   = (int*)(epk + N_EDGES);               // 100,004 i
    int*   cur   = off + 100004;                        // 100,000 i
    int*   bsums = cur + N_NODES;                       // 128 i
    int*   bbase = bsums + 128;                         // 128 i
    unsigned short* Wg = (unsigned short*)(bbase + 128);// 65,536 us (128 KB)

    // --- CSR build ---
    zerok<<<128, 256, 0, stream>>>((float4*)cur, N_NODES / 4);
    histk<<<(N_EDGES + 255) / 256, 256, 0, stream>>>(edst, cur);
    scan_bsum<<<SCAN_NB, 256, 0, stream>>>(cur, bsums);
    scan_top<<<1, 128, 0, stream>>>(bsums, bbase, off);
    scan_final<<<SCAN_NB, 256, 0, stream>>>(cur, bbase, off, cur);
    scatterk<<<(N_EDGES + 255) / 256, 256, 0, stream>>>(esrc, edst, eval_, cur, epk);

    // --- W1 fragment prep + layer 1 ---
    prep_w1<<<(F_IN * HID + 255) / 256, 256, 0, stream>>>(W1, Wg);
    gemm1_mfma<<<(N_NODES + BM - 1) / BM, 256, 0, stream>>>(x, Wg, sup1);
    spmm1_fused<<<N_NODES / 4, 256, 0, stream>>>(off, epk, sup1, b1, W2, sup2);

    // --- layer 2 + softmax ---
    spmm2_softmax<<<(N_NODES + 15) / 16, 256, 0, stream>>>(off, epk, sup2, b2, out);
}

// Round 6
// 315.549 us; speedup vs baseline: 5.7381x; 1.2700x over previous
//
#include <hip/hip_runtime.h>
#include <hip/hip_bf16.h>

#define N_NODES 100000
#define N_EDGES 1600000
#define F_IN    512
#define HID     64
#define NCLS    16

#define SCAN_NB 98      // ceil(100000 / 1024) = # of 1024-node buckets
#define BM      128     // gemm1 row tile
#define PA_EPB  4096    // partA edges per block
#define PA_NB   ((N_EDGES + PA_EPB - 1) / PA_EPB)   // 391

typedef __attribute__((ext_vector_type(8))) short short8;
typedef __attribute__((ext_vector_type(4))) float f32x4;
typedef unsigned int u32;
typedef unsigned short u16;

// ---------------------------------------------------------------------------
// async global->LDS 16B (wave-uniform LDS base + lane*16 dest semantics)
// ---------------------------------------------------------------------------
__device__ inline void gload_lds16(const float* g, float* l) {
    __builtin_amdgcn_global_load_lds(
        (const __attribute__((address_space(1))) u32*)g,
        (__attribute__((address_space(3))) u32*)l, 16, 0, 0);
}

// ---------------------------------------------------------------------------
// zero-fill (float4 grid-stride)
// ---------------------------------------------------------------------------
__global__ void zerok(float4* __restrict__ p, int n4) {
    int i = blockIdx.x * blockDim.x + threadIdx.x;
    int stride = gridDim.x * blockDim.x;
    for (; i < n4; i += stride) p[i] = make_float4(0.f, 0.f, 0.f, 0.f);
}

// ---------------------------------------------------------------------------
// CSR build step 1: histogram of edge_dst
// ---------------------------------------------------------------------------
__global__ __launch_bounds__(256) void histk(const int* __restrict__ edst,
                                             int* __restrict__ cnt) {
    int e = blockIdx.x * 256 + threadIdx.x;
    if (e < N_EDGES) atomicAdd(&cnt[edst[e]], 1);
}

// ---------------------------------------------------------------------------
// CSR build step 2a: per-bucket sums (1024 nodes / bucket)
// ---------------------------------------------------------------------------
__global__ __launch_bounds__(256) void scan_bsum(const int* __restrict__ cnt,
                                                 int* __restrict__ bsums) {
    __shared__ int sc[256];
    int t = threadIdx.x;
    int i0 = blockIdx.x * 1024 + t * 4;
    int s = 0;
    #pragma unroll
    for (int j = 0; j < 4; j++) {
        int i = i0 + j;
        if (i < N_NODES) s += cnt[i];
    }
    sc[t] = s;
    __syncthreads();
    #pragma unroll
    for (int d = 1; d < 256; d <<= 1) {
        int v = (t >= d) ? sc[t - d] : 0;
        __syncthreads();
        sc[t] += v;
        __syncthreads();
    }
    if (t == 255) bsums[blockIdx.x] = sc[255];
}

// ---------------------------------------------------------------------------
// CSR build step 2b: exclusive scan of bucket sums -> bbase (bucket edge
// offsets), also initializes the phase-A global bucket cursors gcur.
// ---------------------------------------------------------------------------
__global__ __launch_bounds__(128) void scan_top(const int* __restrict__ bsums,
                                                int* __restrict__ bbase,
                                                int* __restrict__ gcur,
                                                int* __restrict__ off) {
    __shared__ int sc[128];
    int t = threadIdx.x;
    int v0 = (t < SCAN_NB) ? bsums[t] : 0;
    sc[t] = v0;
    __syncthreads();
    #pragma unroll
    for (int d = 1; d < 128; d <<= 1) {
        int v = (t >= d) ? sc[t - d] : 0;
        __syncthreads();
        sc[t] += v;
        __syncthreads();
    }
    int ex = sc[t] - v0;
    bbase[t] = ex;
    if (t < SCAN_NB) gcur[t] = ex;
    if (t == 0) off[N_NODES] = N_EDGES;
}

// ---------------------------------------------------------------------------
// CSR build step 2c: full exclusive scan -> off[]
// ---------------------------------------------------------------------------
__global__ __launch_bounds__(256) void scan_final(const int* __restrict__ cnt,
                                                  const int* __restrict__ bbase,
                                                  int* __restrict__ off) {
    __shared__ int sc[256];
    int t = threadIdx.x;
    int i0 = blockIdx.x * 1024 + t * 4;
    int c[4];
    int s = 0;
    #pragma unroll
    for (int j = 0; j < 4; j++) {
        int i = i0 + j;
        c[j] = (i < N_NODES) ? cnt[i] : 0;
        s += c[j];
    }
    int tsum = s;
    sc[t] = tsum;
    __syncthreads();
    #pragma unroll
    for (int d = 1; d < 256; d <<= 1) {
        int v = (t >= d) ? sc[t - d] : 0;
        __syncthreads();
        sc[t] += v;
        __syncthreads();
    }
    int base = bbase[blockIdx.x] + sc[t] - tsum;
    #pragma unroll
    for (int j = 0; j < 4; j++) {
        int i = i0 + j;
        if (i < N_NODES) off[i] = base;
        base += c[j];
    }
}

// ---------------------------------------------------------------------------
// CSR build step 3a (partition phase A): bucket edges by dst>>10 into mid[].
// Per block: LDS histogram over 98 buckets -> one global atomic reservation
// per (block,bucket) -> LDS-cursor scatter. Writes are per-(block,bucket)
// contiguous runs => dense cachelines (vs 8x amplified random scatter).
// mid.x packs src (17b) | dst_low10 << 17 ; mid.y = val bits.
// ---------------------------------------------------------------------------
__global__ __launch_bounds__(256) void partA(const int* __restrict__ esrc,
                                             const int* __restrict__ edst,
                                             const float* __restrict__ eval_,
                                             int* __restrict__ gcur,
                                             int2* __restrict__ mid) {
    __shared__ int hist[SCAN_NB];
    int tid = threadIdx.x;
    int e00 = blockIdx.x * PA_EPB;

    for (int i = tid; i < SCAN_NB; i += 256) hist[i] = 0;
    __syncthreads();

    // pass 1: block-local bucket histogram
    #pragma unroll
    for (int j = 0; j < PA_EPB / 256; j++) {
        int e = e00 + j * 256 + tid;
        if (e < N_EDGES) atomicAdd(&hist[edst[e] >> 10], 1);
    }
    __syncthreads();

    // reserve global ranges; hist[b] becomes this block's running cursor
    for (int i = tid; i < SCAN_NB; i += 256) {
        int c = hist[i];
        hist[i] = c ? atomicAdd(&gcur[i], c) : 0;
    }
    __syncthreads();

    // pass 2: scatter into reserved ranges via LDS cursors
    #pragma unroll
    for (int j = 0; j < PA_EPB / 256; j++) {
        int e = e00 + j * 256 + tid;
        if (e < N_EDGES) {
            int d = edst[e];
            int b = d >> 10;
            int pos = atomicAdd(&hist[b], 1);
            mid[pos] = make_int2(esrc[e] | ((d & 1023) << 17),
                                 __float_as_int(eval_[e]));
        }
    }
}

// ---------------------------------------------------------------------------
// CSR build step 3b (phase B): within each bucket, scatter to final dst-
// sorted epk. One block per bucket; node cursors in LDS (zero global
// atomics); final write window is ~130 KB contiguous => L2-dense.
// ---------------------------------------------------------------------------
__global__ __launch_bounds__(512) void partB(const int* __restrict__ bbase,
                                             const int* __restrict__ bsums,
                                             const int* __restrict__ off,
                                             const int2* __restrict__ mid,
                                             int2* __restrict__ epk) {
    __shared__ int curs[1024];
    int tid = threadIdx.x;
    int b   = blockIdx.x;
    int start = bbase[b];
    int cntb  = bsums[b];

    for (int i = tid; i < 1024; i += 512) {
        int node = (b << 10) + i;
        curs[i] = (node < N_NODES) ? off[node] : 0;
    }
    __syncthreads();

    for (int idx = tid; idx < cntb; idx += 512) {
        int2 m = mid[start + idx];
        u32 ux  = (u32)m.x;
        int dlow = ux >> 17;
        int src  = ux & 0x1FFFF;
        int pos = atomicAdd(&curs[dlow], 1);
        epk[pos] = make_int2(src, m.y);
    }
}

// ---------------------------------------------------------------------------
// split fp32 -> bf16 hi + bf16 lo (truncation; residual ~2^-16 relative)
// ---------------------------------------------------------------------------
__device__ inline void split_bf16(float a, unsigned short& hi, unsigned short& lo) {
    unsigned u = __float_as_uint(a);
    hi = (unsigned short)(u >> 16);
    float hif = __uint_as_float(((unsigned)hi) << 16);
    float lof = a - hif;
    lo = (unsigned short)(__float_as_uint(lof) >> 16);
}

// split 8 fp32 (two f32x4) into hi/lo short8 fragments
__device__ inline void split8(f32x4 a, f32x4 b, short8& hi, short8& lo) {
    #pragma unroll
    for (int i = 0; i < 4; i++) {
        u16 h, l;
        split_bf16(a[i], h, l);
        hi[i] = (short)h; lo[i] = (short)l;
    }
    #pragma unroll
    for (int i = 0; i < 4; i++) {
        u16 h, l;
        split_bf16(b[i], h, l);
        hi[4 + i] = (short)h; lo[4 + i] = (short)l;
    }
}

// ---------------------------------------------------------------------------
// prep: W1 [512][64] fp32 -> Wg fragment-native bf16 hi/lo layout
// Wg[nt(4)][kc(16)][h(2)][lane(64)][j(8)] ushort:
//   lane l loads 16B holding n = nt*16 + (l&15), k = kc*32 + (l>>4)*8 + j
// ---------------------------------------------------------------------------
__global__ __launch_bounds__(256) void prep_w1(const float* __restrict__ W1,
                                               unsigned short* __restrict__ Wg) {
    int idx = blockIdx.x * 256 + threadIdx.x;   // 0 .. 32767
    if (idx >= F_IN * HID) return;
    int k = idx >> 6, n = idx & 63;
    unsigned short hi, lo;
    split_bf16(W1[idx], hi, lo);
    int nt = n >> 4, kc = k >> 5;
    int l  = ((k >> 3) & 3) * 16 + (n & 15);
    int j  = k & 7;
    long base = ((((long)nt * 16 + kc) * 2) * 64 + l) * 8 + j;
    Wg[base]       = hi;
    Wg[base + 512] = lo;
}

// ---------------------------------------------------------------------------
// GEMM1: support = x @ W1 via split-bf16 MFMA. 128-row tile, 4 waves.
// x staged fp32 via global_load_lds, 16B-chunk XOR swizzle (inverse on src).
// ---------------------------------------------------------------------------
__global__ __launch_bounds__(256, 2) void gemm1_mfma(const float* __restrict__ x,
                                                     const unsigned short* __restrict__ Wg,
                                                     float* __restrict__ support) {
    __shared__ float tile[BM * 64];   // 32 KB

    const int tid  = threadIdx.x;
    const int l    = tid & 63;
    const int w    = tid >> 6;
    const int lr   = l & 15;
    const int lg   = l >> 4;
    const int row0 = blockIdx.x * BM;

    f32x4 acc[2][4] = {};

    for (int kb = 0; kb < F_IN; kb += 64) {
        // --- stage: 2048 16B slots via global_load_lds ---
        #pragma unroll
        for (int j = 0; j < 8; j++) {
            int slotbase = j * 256 + w * 64;        // wave-uniform
            int slot     = slotbase + l;
            int row      = slot >> 4;
            int cl       = (slot & 15) ^ (row & 7); // inverse swizzle on src
            int rr       = row0 + row;
            if (rr > N_NODES - 1) rr = N_NODES - 1; // clamp (rows >= N discarded)
            gload_lds16(x + (long)rr * F_IN + kb + cl * 4, tile + slotbase * 4);
        }
        __syncthreads();

        #pragma unroll
        for (int ks = 0; ks < 2; ks++) {
            int kc = (kb >> 5) + ks;
            short8 ah[2], al[2];
            #pragma unroll
            for (int m = 0; m < 2; m++) {
                int r  = m * 64 + w * 16 + lr;
                int c0 = ks * 8 + lg * 2;
                f32x4 v0 = *(const f32x4*)&tile[r * 64 + ((c0 ^ (r & 7)) << 2)];
                f32x4 v1 = *(const f32x4*)&tile[r * 64 + (((c0 + 1) ^ (r & 7)) << 2)];
                split8(v0, v1, ah[m], al[m]);
            }
            #pragma unroll
            for (int nt = 0; nt < 4; nt++) {
                long bo = ((((long)nt * 16 + kc) * 2) * 64 + l) * 8;
                short8 bh = *(const short8*)(Wg + bo);
                short8 bl = *(const short8*)(Wg + bo + 512);
                #pragma unroll
                for (int m = 0; m < 2; m++) {
                    acc[m][nt] = __builtin_amdgcn_mfma_f32_16x16x32_bf16(ah[m], bh, acc[m][nt], 0, 0, 0);
                    acc[m][nt] = __builtin_amdgcn_mfma_f32_16x16x32_bf16(ah[m], bl, acc[m][nt], 0, 0, 0);
                    acc[m][nt] = __builtin_amdgcn_mfma_f32_16x16x32_bf16(al[m], bh, acc[m][nt], 0, 0, 0);
                }
            }
        }
        __syncthreads();
    }

    // epilogue: C/D layout col = lane&15, row = (lane>>4)*4 + reg
    #pragma unroll
    for (int m = 0; m < 2; m++) {
        #pragma unroll
        for (int nt = 0; nt < 4; nt++) {
            #pragma unroll
            for (int r = 0; r < 4; r++) {
                int row = row0 + m * 64 + w * 16 + lg * 4 + r;
                if (row < N_NODES)
                    support[(long)row * HID + nt * 16 + lr] = acc[m][nt][r];
            }
        }
    }
}

// ---------------------------------------------------------------------------
// SPMM1 + bias + relu + GEMM2 fused, unroll-4 gathers for MLP:
//   sup2[n] = relu( sum_e val*sup1[src] + b1 ) @ W2
// ---------------------------------------------------------------------------
__global__ __launch_bounds__(256) void spmm1_fused(const int* __restrict__ off,
                                                   const int2* __restrict__ epk,
                                                   const float* __restrict__ sup,
                                                   const float* __restrict__ b1,
                                                   const float* __restrict__ W2,
                                                   float* __restrict__ sup2) {
    __shared__ float w2s[HID * NCLS];   // [k][c]
    __shared__ float hrow[4][HID];
    int tid = threadIdx.x;
    for (int i = tid; i < HID * NCLS; i += 256) w2s[i] = W2[i];
    __syncthreads();

    int lane = tid & 63;
    int w    = tid >> 6;
    int n    = blockIdx.x * 4 + w;      // grid exact: N_NODES % 4 == 0

    int e0 = off[n];
    int e1 = off[n + 1];
    float acc = 0.f;
    int e = e0;
    for (; e + 3 < e1; e += 4) {
        int2 p0 = epk[e],     p1 = epk[e + 1];
        int2 p2 = epk[e + 2], p3 = epk[e + 3];
        float g0 = sup[(long)p0.x * HID + lane];
        float g1 = sup[(long)p1.x * HID + lane];
        float g2 = sup[(long)p2.x * HID + lane];
        float g3 = sup[(long)p3.x * HID + lane];
        acc += __int_as_float(p0.y) * g0 + __int_as_float(p1.y) * g1
             + __int_as_float(p2.y) * g2 + __int_as_float(p3.y) * g3;
    }
    for (; e < e1; e++) {
        int2 p = epk[e];
        acc += __int_as_float(p.y) * sup[(long)p.x * HID + lane];
    }
    float hv = fmaxf(acc + b1[lane], 0.f);

    hrow[w][lane] = hv;
    asm volatile("s_waitcnt lgkmcnt(0)" ::: "memory");   // wave-local LDS drain
    __builtin_amdgcn_sched_barrier(0);                   // rule #18 fence

    int c = lane & 15, q = lane >> 4;
    float part = 0.f;
    #pragma unroll
    for (int k0 = 0; k0 < 16; k0++) {
        int k = q * 16 + k0;
        part += hrow[w][k] * w2s[k * NCLS + c];
    }
    part += __shfl_xor(part, 16);
    part += __shfl_xor(part, 32);
    if (lane < 16) sup2[(long)n * NCLS + c] = part;
}

// ---------------------------------------------------------------------------
// SPMM2 (CSR) fused with +b2 and softmax, unroll-4. 16 lanes per node.
// ---------------------------------------------------------------------------
__global__ __launch_bounds__(256) void spmm2_softmax(const int* __restrict__ off,
                                                     const int2* __restrict__ epk,
                                                     const float* __restrict__ sup2,
                                                     const float* __restrict__ b2,
                                                     float* __restrict__ out) {
    int tid = threadIdx.x;
    int n   = blockIdx.x * 16 + (tid >> 4);
    int c   = tid & 15;
    if (n >= N_NODES) return;

    int e0 = off[n];
    int e1 = off[n + 1];
    float acc = 0.f;
    int e = e0;
    for (; e + 3 < e1; e += 4) {
        int2 p0 = epk[e],     p1 = epk[e + 1];
        int2 p2 = epk[e + 2], p3 = epk[e + 3];
        float g0 = sup2[(long)p0.x * NCLS + c];
        float g1 = sup2[(long)p1.x * NCLS + c];
        float g2 = sup2[(long)p2.x * NCLS + c];
        float g3 = sup2[(long)p3.x * NCLS + c];
        acc += __int_as_float(p0.y) * g0 + __int_as_float(p1.y) * g1
             + __int_as_float(p2.y) * g2 + __int_as_float(p3.y) * g3;
    }
    for (; e < e1; e++) {
        int2 p = epk[e];
        acc += __int_as_float(p.y) * sup2[(long)p.x * NCLS + c];
    }

    float lg = acc + b2[c];
    float m = lg;
    #pragma unroll
    for (int mask = 1; mask < 16; mask <<= 1)
        m = fmaxf(m, __shfl_xor(m, mask, 16));
    float p = expf(lg - m);
    float s = p;
    #pragma unroll
    for (int mask = 1; mask < 16; mask <<= 1)
        s += __shfl_xor(s, mask, 16);
    out[(long)n * NCLS + c] = p / s;
}

// ---------------------------------------------------------------------------
extern "C" void kernel_launch(void* const* d_in, const int* in_sizes, int n_in,
                              void* d_out, int out_size, void* d_ws, size_t ws_size,
                              hipStream_t stream) {
    const float* x     = (const float*)d_in[0];
    const int*   esrc  = (const int*)  d_in[1];
    const int*   edst  = (const int*)  d_in[2];
    const float* eval_ = (const float*)d_in[3];
    const float* W1    = (const float*)d_in[4];
    const float* b1    = (const float*)d_in[5];
    const float* W2    = (const float*)d_in[6];
    const float* b2    = (const float*)d_in[7];
    float* out = (float*)d_out;

    // workspace layout (4B units; every base 16B-aligned)
    float* sup1  = (float*)d_ws;                        // 6,400,000 f
    float* sup2  = sup1 + (long)N_NODES * HID;          // 1,600,000 f
    int2*  epk   = (int2*)(sup2 + (long)N_NODES * NCLS);// 1,600,000 int2
    int*   off   = (int*)(epk + N_EDGES);               // 100,004 i
    int*   cnt   = off + 100004;                        // 100,000 i
    int*   bsums = cnt + N_NODES;                       // 128 i
    int*   bbase = bsums + 128;                         // 128 i
    int*   gcur  = bbase + 128;                         // 128 i
    unsigned short* Wg = (unsigned short*)(gcur + 128); // 65,536 us (128 KB)
    int2*  mid   = (int2*)(Wg + 65536);                 // 1,600,000 int2

    // --- CSR build ---
    zerok<<<128, 256, 0, stream>>>((float4*)cnt, N_NODES / 4);
    histk<<<(N_EDGES + 255) / 256, 256, 0, stream>>>(edst, cnt);
    scan_bsum<<<SCAN_NB, 256, 0, stream>>>(cnt, bsums);
    scan_top<<<1, 128, 0, stream>>>(bsums, bbase, gcur, off);
    scan_final<<<SCAN_NB, 256, 0, stream>>>(cnt, bbase, off);
    partA<<<PA_NB, 256, 0, stream>>>(esrc, edst, eval_, gcur, mid);
    partB<<<SCAN_NB, 512, 0, stream>>>(bbase, bsums, off, mid, epk);

    // --- W1 fragment prep + layer 1 ---
    prep_w1<<<(F_IN * HID + 255) / 256, 256, 0, stream>>>(W1, Wg);
    gemm1_mfma<<<(N_NODES + BM - 1) / BM, 256, 0, stream>>>(x, Wg, sup1);
    spmm1_fused<<<N_NODES / 4, 256, 0, stream>>>(off, epk, sup1, b1, W2, sup2);

    // --- layer 2 + softmax ---
    spmm2_softmax<<<(N_NODES + 15) / 16, 256, 0, stream>>>(off, epk, sup2, b2, out);
}

// Round 7
// 293.239 us; speedup vs baseline: 6.1747x; 1.0761x over previous
//
#include <hip/hip_runtime.h>
#include <hip/hip_bf16.h>

#define N_NODES 100000
#define N_EDGES 1600000
#define F_IN    512
#define HID     64
#define NCLS    16

#define SCAN_NB 98      // ceil(100000 / 1024) = # of 1024-node buckets
#define BM      128     // gemm1 row tile
#define BK      128     // gemm1 k tile (2 barrier-pairs per 256 K)
#define PA_EPB  4096    // partA edges per block
#define PA_NB   ((N_EDGES + PA_EPB - 1) / PA_EPB)   // 391

typedef __attribute__((ext_vector_type(8))) short short8;
typedef __attribute__((ext_vector_type(4))) float f32x4;
typedef unsigned int u32;
typedef unsigned short u16;

// ---------------------------------------------------------------------------
// async global->LDS 16B (wave-uniform LDS base + lane*16 dest semantics)
// ---------------------------------------------------------------------------
__device__ inline void gload_lds16(const float* g, float* l) {
    __builtin_amdgcn_global_load_lds(
        (const __attribute__((address_space(1))) u32*)g,
        (__attribute__((address_space(3))) u32*)l, 16, 0, 0);
}

// ---------------------------------------------------------------------------
// zero-fill (float4 grid-stride)
// ---------------------------------------------------------------------------
__global__ void zerok(float4* __restrict__ p, int n4) {
    int i = blockIdx.x * blockDim.x + threadIdx.x;
    int stride = gridDim.x * blockDim.x;
    for (; i < n4; i += stride) p[i] = make_float4(0.f, 0.f, 0.f, 0.f);
}

// ---------------------------------------------------------------------------
// CSR build step 1: histogram of edge_dst
// ---------------------------------------------------------------------------
__global__ __launch_bounds__(256) void histk(const int* __restrict__ edst,
                                             int* __restrict__ cnt) {
    int e = blockIdx.x * 256 + threadIdx.x;
    if (e < N_EDGES) atomicAdd(&cnt[edst[e]], 1);
}

// ---------------------------------------------------------------------------
// CSR build step 2a: per-bucket sums (1024 nodes / bucket)
// ---------------------------------------------------------------------------
__global__ __launch_bounds__(256) void scan_bsum(const int* __restrict__ cnt,
                                                 int* __restrict__ bsums) {
    __shared__ int sc[256];
    int t = threadIdx.x;
    int i0 = blockIdx.x * 1024 + t * 4;
    int s = 0;
    #pragma unroll
    for (int j = 0; j < 4; j++) {
        int i = i0 + j;
        if (i < N_NODES) s += cnt[i];
    }
    sc[t] = s;
    __syncthreads();
    #pragma unroll
    for (int d = 1; d < 256; d <<= 1) {
        int v = (t >= d) ? sc[t - d] : 0;
        __syncthreads();
        sc[t] += v;
        __syncthreads();
    }
    if (t == 255) bsums[blockIdx.x] = sc[255];
}

// ---------------------------------------------------------------------------
// CSR build step 2b: exclusive scan of bucket sums -> bbase; init gcur.
// ---------------------------------------------------------------------------
__global__ __launch_bounds__(128) void scan_top(const int* __restrict__ bsums,
                                                int* __restrict__ bbase,
                                                int* __restrict__ gcur,
                                                int* __restrict__ off) {
    __shared__ int sc[128];
    int t = threadIdx.x;
    int v0 = (t < SCAN_NB) ? bsums[t] : 0;
    sc[t] = v0;
    __syncthreads();
    #pragma unroll
    for (int d = 1; d < 128; d <<= 1) {
        int v = (t >= d) ? sc[t - d] : 0;
        __syncthreads();
        sc[t] += v;
        __syncthreads();
    }
    int ex = sc[t] - v0;
    bbase[t] = ex;
    if (t < SCAN_NB) gcur[t] = ex;
    if (t == 0) off[N_NODES] = N_EDGES;
}

// ---------------------------------------------------------------------------
// CSR build step 2c: full exclusive scan -> off[]
// ---------------------------------------------------------------------------
__global__ __launch_bounds__(256) void scan_final(const int* __restrict__ cnt,
                                                  const int* __restrict__ bbase,
                                                  int* __restrict__ off) {
    __shared__ int sc[256];
    int t = threadIdx.x;
    int i0 = blockIdx.x * 1024 + t * 4;
    int c[4];
    int s = 0;
    #pragma unroll
    for (int j = 0; j < 4; j++) {
        int i = i0 + j;
        c[j] = (i < N_NODES) ? cnt[i] : 0;
        s += c[j];
    }
    int tsum = s;
    sc[t] = tsum;
    __syncthreads();
    #pragma unroll
    for (int d = 1; d < 256; d <<= 1) {
        int v = (t >= d) ? sc[t - d] : 0;
        __syncthreads();
        sc[t] += v;
        __syncthreads();
    }
    int base = bbase[blockIdx.x] + sc[t] - tsum;
    #pragma unroll
    for (int j = 0; j < 4; j++) {
        int i = i0 + j;
        if (i < N_NODES) off[i] = base;
        base += c[j];
    }
}

// ---------------------------------------------------------------------------
// CSR build step 3a (partition phase A): bucket edges by dst>>10 into mid[].
// mid.x packs src (17b) | dst_low10 << 17 ; mid.y = val bits.
// ---------------------------------------------------------------------------
__global__ __launch_bounds__(256) void partA(const int* __restrict__ esrc,
                                             const int* __restrict__ edst,
                                             const float* __restrict__ eval_,
                                             int* __restrict__ gcur,
                                             int2* __restrict__ mid) {
    __shared__ int hist[SCAN_NB];
    int tid = threadIdx.x;
    int e00 = blockIdx.x * PA_EPB;

    for (int i = tid; i < SCAN_NB; i += 256) hist[i] = 0;
    __syncthreads();

    #pragma unroll
    for (int j = 0; j < PA_EPB / 256; j++) {
        int e = e00 + j * 256 + tid;
        if (e < N_EDGES) atomicAdd(&hist[edst[e] >> 10], 1);
    }
    __syncthreads();

    for (int i = tid; i < SCAN_NB; i += 256) {
        int c = hist[i];
        hist[i] = c ? atomicAdd(&gcur[i], c) : 0;
    }
    __syncthreads();

    #pragma unroll
    for (int j = 0; j < PA_EPB / 256; j++) {
        int e = e00 + j * 256 + tid;
        if (e < N_EDGES) {
            int d = edst[e];
            int b = d >> 10;
            int pos = atomicAdd(&hist[b], 1);
            mid[pos] = make_int2(esrc[e] | ((d & 1023) << 17),
                                 __float_as_int(eval_[e]));
        }
    }
}

// ---------------------------------------------------------------------------
// CSR build step 3b (phase B): within-bucket scatter to final epk.
// ---------------------------------------------------------------------------
__global__ __launch_bounds__(512) void partB(const int* __restrict__ bbase,
                                             const int* __restrict__ bsums,
                                             const int* __restrict__ off,
                                             const int2* __restrict__ mid,
                                             int2* __restrict__ epk) {
    __shared__ int curs[1024];
    int tid = threadIdx.x;
    int b   = blockIdx.x;
    int start = bbase[b];
    int cntb  = bsums[b];

    for (int i = tid; i < 1024; i += 512) {
        int node = (b << 10) + i;
        curs[i] = (node < N_NODES) ? off[node] : 0;
    }
    __syncthreads();

    for (int idx = tid; idx < cntb; idx += 512) {
        int2 m = mid[start + idx];
        u32 ux  = (u32)m.x;
        int dlow = ux >> 17;
        int src  = ux & 0x1FFFF;
        int pos = atomicAdd(&curs[dlow], 1);
        epk[pos] = make_int2(src, m.y);
    }
}

// ---------------------------------------------------------------------------
// split fp32 -> bf16 hi + bf16 lo (truncation; residual ~2^-16 relative)
// ---------------------------------------------------------------------------
__device__ inline void split_bf16(float a, unsigned short& hi, unsigned short& lo) {
    unsigned u = __float_as_uint(a);
    hi = (unsigned short)(u >> 16);
    float hif = __uint_as_float(((unsigned)hi) << 16);
    float lof = a - hif;
    lo = (unsigned short)(__float_as_uint(lof) >> 16);
}

// split 8 fp32 (two f32x4) into hi/lo short8 fragments
__device__ inline void split8(f32x4 a, f32x4 b, short8& hi, short8& lo) {
    #pragma unroll
    for (int i = 0; i < 4; i++) {
        u16 h, l;
        split_bf16(a[i], h, l);
        hi[i] = (short)h; lo[i] = (short)l;
    }
    #pragma unroll
    for (int i = 0; i < 4; i++) {
        u16 h, l;
        split_bf16(b[i], h, l);
        hi[4 + i] = (short)h; lo[4 + i] = (short)l;
    }
}

// ---------------------------------------------------------------------------
// prep: W1 [512][64] fp32 -> Wg fragment-native bf16 hi/lo layout
// Wg[nt(4)][kc(16)][h(2)][lane(64)][j(8)] ushort:
//   lane l loads 16B holding n = nt*16 + (l&15), k = kc*32 + (l>>4)*8 + j
// ---------------------------------------------------------------------------
__global__ __launch_bounds__(256) void prep_w1(const float* __restrict__ W1,
                                               unsigned short* __restrict__ Wg) {
    int idx = blockIdx.x * 256 + threadIdx.x;   // 0 .. 32767
    if (idx >= F_IN * HID) return;
    int k = idx >> 6, n = idx & 63;
    unsigned short hi, lo;
    split_bf16(W1[idx], hi, lo);
    int nt = n >> 4, kc = k >> 5;
    int l  = ((k >> 3) & 3) * 16 + (n & 15);
    int j  = k & 7;
    long base = ((((long)nt * 16 + kc) * 2) * 64 + l) * 8 + j;
    Wg[base]       = hi;
    Wg[base + 512] = lo;
}

// ---------------------------------------------------------------------------
// GEMM1: support = x @ W1 via split-bf16 MFMA. 128-row tile, BK=128 K-tile
// (one barrier pair per 128 K -> half the vmcnt(0) drains of BK=64).
// x staged fp32 via global_load_lds; 16B-chunk XOR swizzle (inverse on src;
// 5-bit chunk index, XOR touches only low 3 bits -> stays in row).
// LDS 64 KB; __launch_bounds__(256,2) keeps 2 blocks/CU (128 KB <= 160 KB).
// ---------------------------------------------------------------------------
__global__ __launch_bounds__(256, 2) void gemm1_mfma(const float* __restrict__ x,
                                                     const unsigned short* __restrict__ Wg,
                                                     float* __restrict__ support) {
    __shared__ float tile[BM * BK];   // 64 KB

    const int tid  = threadIdx.x;
    const int l    = tid & 63;
    const int w    = tid >> 6;
    const int lr   = l & 15;
    const int lg   = l >> 4;
    const int row0 = blockIdx.x * BM;

    f32x4 acc[2][4] = {};

    for (int kb = 0; kb < F_IN; kb += BK) {
        // --- stage: 128 rows x 32 chunks = 4096 16B slots ---
        #pragma unroll
        for (int j = 0; j < 16; j++) {
            int slotbase = j * 256 + w * 64;        // wave-uniform
            int slot     = slotbase + l;
            int row      = slot >> 5;               // 32 chunks per row
            int cl       = (slot & 31) ^ (row & 7); // inverse swizzle on src
            int rr       = row0 + row;
            if (rr > N_NODES - 1) rr = N_NODES - 1; // clamp (rows >= N discarded)
            gload_lds16(x + (long)rr * F_IN + kb + cl * 4, tile + slotbase * 4);
        }
        __syncthreads();

        #pragma unroll
        for (int ks = 0; ks < 4; ks++) {
            int kc = (kb >> 5) + ks;
            short8 ah[2], al[2];
            #pragma unroll
            for (int m = 0; m < 2; m++) {
                int r  = m * 64 + w * 16 + lr;
                int c0 = ks * 8 + lg * 2;
                f32x4 v0 = *(const f32x4*)&tile[r * BK + ((c0 ^ (r & 7)) << 2)];
                f32x4 v1 = *(const f32x4*)&tile[r * BK + (((c0 + 1) ^ (r & 7)) << 2)];
                split8(v0, v1, ah[m], al[m]);
            }
            #pragma unroll
            for (int nt = 0; nt < 4; nt++) {
                long bo = ((((long)nt * 16 + kc) * 2) * 64 + l) * 8;
                short8 bh = *(const short8*)(Wg + bo);
                short8 bl = *(const short8*)(Wg + bo + 512);
                #pragma unroll
                for (int m = 0; m < 2; m++) {
                    acc[m][nt] = __builtin_amdgcn_mfma_f32_16x16x32_bf16(ah[m], bh, acc[m][nt], 0, 0, 0);
                    acc[m][nt] = __builtin_amdgcn_mfma_f32_16x16x32_bf16(ah[m], bl, acc[m][nt], 0, 0, 0);
                    acc[m][nt] = __builtin_amdgcn_mfma_f32_16x16x32_bf16(al[m], bh, acc[m][nt], 0, 0, 0);
                }
            }
        }
        __syncthreads();
    }

    // epilogue: C/D layout col = lane&15, row = (lane>>4)*4 + reg
    #pragma unroll
    for (int m = 0; m < 2; m++) {
        #pragma unroll
        for (int nt = 0; nt < 4; nt++) {
            #pragma unroll
            for (int r = 0; r < 4; r++) {
                int row = row0 + m * 64 + w * 16 + lg * 4 + r;
                if (row < N_NODES)
                    support[(long)row * HID + nt * 16 + lr] = acc[m][nt][r];
            }
        }
    }
}

// ---------------------------------------------------------------------------
// SPMM1 + bias + relu + GEMM2 fused, unroll-8 gathers (latency-bound MLP):
//   sup2[n] = relu( sum_e val*sup1[src] + b1 ) @ W2
// ---------------------------------------------------------------------------
__global__ __launch_bounds__(256) void spmm1_fused(const int* __restrict__ off,
                                                   const int2* __restrict__ epk,
                                                   const float* __restrict__ sup,
                                                   const float* __restrict__ b1,
                                                   const float* __restrict__ W2,
                                                   float* __restrict__ sup2) {
    __shared__ float w2s[HID * NCLS];   // [k][c]
    __shared__ float hrow[4][HID];
    int tid = threadIdx.x;
    for (int i = tid; i < HID * NCLS; i += 256) w2s[i] = W2[i];
    __syncthreads();

    int lane = tid & 63;
    int w    = tid >> 6;
    int n    = blockIdx.x * 4 + w;      // grid exact: N_NODES % 4 == 0

    int e0 = off[n];
    int e1 = off[n + 1];
    float acc = 0.f;
    int e = e0;
    for (; e + 7 < e1; e += 8) {
        int2 p[8];
        float g[8];
        #pragma unroll
        for (int j = 0; j < 8; j++) p[j] = epk[e + j];
        #pragma unroll
        for (int j = 0; j < 8; j++) g[j] = sup[(long)p[j].x * HID + lane];
        #pragma unroll
        for (int j = 0; j < 8; j++) acc += __int_as_float(p[j].y) * g[j];
    }
    for (; e + 3 < e1; e += 4) {
        int2 p0 = epk[e],     p1 = epk[e + 1];
        int2 p2 = epk[e + 2], p3 = epk[e + 3];
        float g0 = sup[(long)p0.x * HID + lane];
        float g1 = sup[(long)p1.x * HID + lane];
        float g2 = sup[(long)p2.x * HID + lane];
        float g3 = sup[(long)p3.x * HID + lane];
        acc += __int_as_float(p0.y) * g0 + __int_as_float(p1.y) * g1
             + __int_as_float(p2.y) * g2 + __int_as_float(p3.y) * g3;
    }
    for (; e < e1; e++) {
        int2 p = epk[e];
        acc += __int_as_float(p.y) * sup[(long)p.x * HID + lane];
    }
    float hv = fmaxf(acc + b1[lane], 0.f);

    hrow[w][lane] = hv;
    asm volatile("s_waitcnt lgkmcnt(0)" ::: "memory");   // wave-local LDS drain
    __builtin_amdgcn_sched_barrier(0);                   // rule #18 fence

    int c = lane & 15, q = lane >> 4;
    float part = 0.f;
    #pragma unroll
    for (int k0 = 0; k0 < 16; k0++) {
        int k = q * 16 + k0;
        part += hrow[w][k] * w2s[k * NCLS + c];
    }
    part += __shfl_xor(part, 16);
    part += __shfl_xor(part, 32);
    if (lane < 16) sup2[(long)n * NCLS + c] = part;
}

// ---------------------------------------------------------------------------
// SPMM2 (CSR) fused with +b2 and softmax, unroll-8. 16 lanes per node.
// ---------------------------------------------------------------------------
__global__ __launch_bounds__(256) void spmm2_softmax(const int* __restrict__ off,
                                                     const int2* __restrict__ epk,
                                                     const float* __restrict__ sup2,
                                                     const float* __restrict__ b2,
                                                     float* __restrict__ out) {
    int tid = threadIdx.x;
    int n   = blockIdx.x * 16 + (tid >> 4);
    int c   = tid & 15;
    if (n >= N_NODES) return;

    int e0 = off[n];
    int e1 = off[n + 1];
    float acc = 0.f;
    int e = e0;
    for (; e + 7 < e1; e += 8) {
        int2 p[8];
        float g[8];
        #pragma unroll
        for (int j = 0; j < 8; j++) p[j] = epk[e + j];
        #pragma unroll
        for (int j = 0; j < 8; j++) g[j] = sup2[(long)p[j].x * NCLS + c];
        #pragma unroll
        for (int j = 0; j < 8; j++) acc += __int_as_float(p[j].y) * g[j];
    }
    for (; e + 3 < e1; e += 4) {
        int2 p0 = epk[e],     p1 = epk[e + 1];
        int2 p2 = epk[e + 2], p3 = epk[e + 3];
        float g0 = sup2[(long)p0.x * NCLS + c];
        float g1 = sup2[(long)p1.x * NCLS + c];
        float g2 = sup2[(long)p2.x * NCLS + c];
        float g3 = sup2[(long)p3.x * NCLS + c];
        acc += __int_as_float(p0.y) * g0 + __int_as_float(p1.y) * g1
             + __int_as_float(p2.y) * g2 + __int_as_float(p3.y) * g3;
    }
    for (; e < e1; e++) {
        int2 p = epk[e];
        acc += __int_as_float(p.y) * sup2[(long)p.x * NCLS + c];
    }

    float lg = acc + b2[c];
    float m = lg;
    #pragma unroll
    for (int mask = 1; mask < 16; mask <<= 1)
        m = fmaxf(m, __shfl_xor(m, mask, 16));
    float p = expf(lg - m);
    float s = p;
    #pragma unroll
    for (int mask = 1; mask < 16; mask <<= 1)
        s += __shfl_xor(s, mask, 16);
    out[(long)n * NCLS + c] = p / s;
}

// ---------------------------------------------------------------------------
extern "C" void kernel_launch(void* const* d_in, const int* in_sizes, int n_in,
                              void* d_out, int out_size, void* d_ws, size_t ws_size,
                              hipStream_t stream) {
    const float* x     = (const float*)d_in[0];
    const int*   esrc  = (const int*)  d_in[1];
    const int*   edst  = (const int*)  d_in[2];
    const float* eval_ = (const float*)d_in[3];
    const float* W1    = (const float*)d_in[4];
    const float* b1    = (const float*)d_in[5];
    const float* W2    = (const float*)d_in[6];
    const float* b2    = (const float*)d_in[7];
    float* out = (float*)d_out;

    // workspace layout (4B units; every base 16B-aligned)
    float* sup1  = (float*)d_ws;                        // 6,400,000 f
    float* sup2  = sup1 + (long)N_NODES * HID;          // 1,600,000 f
    int2*  epk   = (int2*)(sup2 + (long)N_NODES * NCLS);// 1,600,000 int2
    int*   off   = (int*)(epk + N_EDGES);               // 100,004 i
    int*   cnt   = off + 100004;                        // 100,000 i
    int*   bsums = cnt + N_NODES;                       // 128 i
    int*   bbase = bsums + 128;                         // 128 i
    int*   gcur  = bbase + 128;                         // 128 i
    unsigned short* Wg = (unsigned short*)(gcur + 128); // 65,536 us (128 KB)
    int2*  mid   = (int2*)(Wg + 65536);                 // 1,600,000 int2

    // --- CSR build ---
    zerok<<<128, 256, 0, stream>>>((float4*)cnt, N_NODES / 4);
    histk<<<(N_EDGES + 255) / 256, 256, 0, stream>>>(edst, cnt);
    scan_bsum<<<SCAN_NB, 256, 0, stream>>>(cnt, bsums);
    scan_top<<<1, 128, 0, stream>>>(bsums, bbase, gcur, off);
    scan_final<<<SCAN_NB, 256, 0, stream>>>(cnt, bbase, off);
    partA<<<PA_NB, 256, 0, stream>>>(esrc, edst, eval_, gcur, mid);
    partB<<<SCAN_NB, 512, 0, stream>>>(bbase, bsums, off, mid, epk);

    // --- W1 fragment prep + layer 1 ---
    prep_w1<<<(F_IN * HID + 255) / 256, 256, 0, stream>>>(W1, Wg);
    gemm1_mfma<<<(N_NODES + BM - 1) / BM, 256, 0, stream>>>(x, Wg, sup1);
    spmm1_fused<<<N_NODES / 4, 256, 0, stream>>>(off, epk, sup1, b1, W2, sup2);

    // --- layer 2 + softmax ---
    spmm2_softmax<<<(N_NODES + 15) / 16, 256, 0, stream>>>(off, epk, sup2, b2, out);
}

// Round 8
// 228.660 us; speedup vs baseline: 7.9185x; 1.2824x over previous
//
#include <hip/hip_runtime.h>
#include <hip/hip_bf16.h>

#define N_NODES 100000
#define N_EDGES 1600000
#define F_IN    512
#define HID     64
#define NCLS    16

#define SCAN_NB 98      // ceil(100000 / 1024) = # of 1024-node buckets
#define BM      128     // gemm1 row tile
#define BK      128     // gemm1 k tile
#define PA_EPB  4096    // partition edges per block
#define PA_NB   ((N_EDGES + PA_EPB - 1) / PA_EPB)   // 391

typedef __attribute__((ext_vector_type(8))) short short8;
typedef __attribute__((ext_vector_type(4))) float f32x4;
typedef unsigned int u32;
typedef unsigned short u16;

// ---------------------------------------------------------------------------
// async global->LDS 16B (wave-uniform LDS base + lane*16 dest semantics)
// ---------------------------------------------------------------------------
__device__ inline void gload_lds16(const float* g, float* l) {
    __builtin_amdgcn_global_load_lds(
        (const __attribute__((address_space(1))) u32*)g,
        (__attribute__((address_space(3))) u32*)l, 16, 0, 0);
}

// ---------------------------------------------------------------------------
// CSR build 1: per-block bucket histogram -> blockhist[bucket][block]
// (LDS atomics only; dense 153 KB store; no global atomics)
// ---------------------------------------------------------------------------
__global__ __launch_bounds__(256) void bhist(const int* __restrict__ edst,
                                             int* __restrict__ bh) {
    __shared__ int hist[SCAN_NB];
    int tid = threadIdx.x;
    int e00 = blockIdx.x * PA_EPB;
    for (int i = tid; i < SCAN_NB; i += 256) hist[i] = 0;
    __syncthreads();
    #pragma unroll
    for (int j = 0; j < PA_EPB / 256; j++) {
        int e = e00 + j * 256 + tid;
        if (e < N_EDGES) atomicAdd(&hist[edst[e] >> 10], 1);
    }
    __syncthreads();
    for (int i = tid; i < SCAN_NB; i += 256)
        bh[i * PA_NB + blockIdx.x] = hist[i];
}

// ---------------------------------------------------------------------------
// CSR build 2: per bucket, exclusive scan over the 391 block counts
// (in place) ; bucket total -> bsums. One block per bucket.
// ---------------------------------------------------------------------------
__global__ __launch_bounds__(512) void colscan(int* __restrict__ bh,
                                               int* __restrict__ bsums) {
    __shared__ int sc[512];
    int t = threadIdx.x;
    int b = blockIdx.x;
    int v = (t < PA_NB) ? bh[b * PA_NB + t] : 0;
    sc[t] = v;
    __syncthreads();
    #pragma unroll
    for (int d = 1; d < 512; d <<= 1) {
        int u = (t >= d) ? sc[t - d] : 0;
        __syncthreads();
        sc[t] += u;
        __syncthreads();
    }
    if (t < PA_NB) bh[b * PA_NB + t] = sc[t] - v;   // exclusive
    if (t == 511) bsums[b] = sc[511];
}

// ---------------------------------------------------------------------------
// CSR build 3: exclusive scan of bucket sums -> bbase; off[N]=E.
// ---------------------------------------------------------------------------
__global__ __launch_bounds__(128) void scan_top(const int* __restrict__ bsums,
                                                int* __restrict__ bbase,
                                                int* __restrict__ off) {
    __shared__ int sc[128];
    int t = threadIdx.x;
    int v0 = (t < SCAN_NB) ? bsums[t] : 0;
    sc[t] = v0;
    __syncthreads();
    #pragma unroll
    for (int d = 1; d < 128; d <<= 1) {
        int v = (t >= d) ? sc[t - d] : 0;
        __syncthreads();
        sc[t] += v;
        __syncthreads();
    }
    bbase[t] = sc[t] - v0;
    if (t == 0) off[N_NODES] = N_EDGES;
}

// ---------------------------------------------------------------------------
// CSR build 4: bucket edges by dst>>10 into mid[]. Deterministic per-block
// reservations (bbase + scanned blockhist); LDS cursors; no global atomics.
// mid.x packs src (17b) | dst_low10 << 17 ; mid.y = val bits.
// ---------------------------------------------------------------------------
__global__ __launch_bounds__(256) void partA2(const int* __restrict__ esrc,
                                              const int* __restrict__ edst,
                                              const float* __restrict__ eval_,
                                              const int* __restrict__ bh,
                                              const int* __restrict__ bbase,
                                              int2* __restrict__ mid) {
    __shared__ int curs[SCAN_NB];
    int tid = threadIdx.x;
    int blk = blockIdx.x;
    int e00 = blk * PA_EPB;
    for (int i = tid; i < SCAN_NB; i += 256)
        curs[i] = bbase[i] + bh[i * PA_NB + blk];
    __syncthreads();
    #pragma unroll
    for (int j = 0; j < PA_EPB / 256; j++) {
        int e = e00 + j * 256 + tid;
        if (e < N_EDGES) {
            int d = edst[e];
            int b = d >> 10;
            int pos = atomicAdd(&curs[b], 1);
            mid[pos] = make_int2(esrc[e] | ((d & 1023) << 17),
                                 __float_as_int(eval_[e]));
        }
    }
}

// ---------------------------------------------------------------------------
// CSR build 5: within-bucket final scatter. Counts node degrees from mid
// (LDS atomics), 1024-wide LDS scan -> off[] AND cursors locally, then
// scatters to epk. Second mid pass hits L2 (~130 KB window). One block
// per bucket; zero global atomics.
// ---------------------------------------------------------------------------
__global__ __launch_bounds__(512) void partB2(const int* __restrict__ bbase,
                                              const int* __restrict__ bsums,
                                              const int2* __restrict__ mid,
                                              int2* __restrict__ epk,
                                              int* __restrict__ off) {
    __shared__ int nh[1024];
    __shared__ int sc[512];
    int t = threadIdx.x;
    int b = blockIdx.x;
    int start = bbase[b];
    int cntb  = bsums[b];

    nh[t] = 0; nh[t + 512] = 0;
    __syncthreads();

    // pass 1: node-degree histogram within bucket
    for (int i = t; i < cntb; i += 512) {
        u32 ux = (u32)mid[start + i].x;
        atomicAdd(&nh[ux >> 17], 1);
    }
    __syncthreads();

    // pair-load counts, 512-wide scan of pair sums
    int c0 = nh[2 * t], c1 = nh[2 * t + 1];
    int s = c0 + c1;
    sc[t] = s;
    __syncthreads();
    #pragma unroll
    for (int d = 1; d < 512; d <<= 1) {
        int u = (t >= d) ? sc[t - d] : 0;
        __syncthreads();
        sc[t] += u;
        __syncthreads();
    }
    int ex = start + sc[t] - s;       // exclusive prefix for node pair

    // overwrite nh with global cursors; emit off[]
    nh[2 * t]     = ex;
    nh[2 * t + 1] = ex + c0;
    int node = (b << 10) + 2 * t;
    if (node < N_NODES)     off[node]     = ex;
    if (node + 1 < N_NODES) off[node + 1] = ex + c0;
    __syncthreads();

    // pass 2: scatter to final dst-sorted order
    for (int i = t; i < cntb; i += 512) {
        int2 m = mid[start + i];
        u32 ux = (u32)m.x;
        int pos = atomicAdd(&nh[ux >> 17], 1);
        epk[pos] = make_int2((int)(ux & 0x1FFFF), m.y);
    }
}

// ---------------------------------------------------------------------------
// split fp32 -> bf16 hi + bf16 lo (truncation; residual ~2^-16 relative)
// ---------------------------------------------------------------------------
__device__ inline void split_bf16(float a, unsigned short& hi, unsigned short& lo) {
    unsigned u = __float_as_uint(a);
    hi = (unsigned short)(u >> 16);
    float hif = __uint_as_float(((unsigned)hi) << 16);
    float lof = a - hif;
    lo = (unsigned short)(__float_as_uint(lof) >> 16);
}

// split 8 fp32 (two f32x4) into hi/lo short8 fragments
__device__ inline void split8(f32x4 a, f32x4 b, short8& hi, short8& lo) {
    #pragma unroll
    for (int i = 0; i < 4; i++) {
        u16 h, l;
        split_bf16(a[i], h, l);
        hi[i] = (short)h; lo[i] = (short)l;
    }
    #pragma unroll
    for (int i = 0; i < 4; i++) {
        u16 h, l;
        split_bf16(b[i], h, l);
        hi[4 + i] = (short)h; lo[4 + i] = (short)l;
    }
}

// ---------------------------------------------------------------------------
// prep: W1 [512][64] fp32 -> Wg fragment-native bf16 hi/lo layout
// Wg[nt(4)][kc(16)][h(2)][lane(64)][j(8)] ushort:
//   lane l loads 16B holding n = nt*16 + (l&15), k = kc*32 + (l>>4)*8 + j
// ---------------------------------------------------------------------------
__global__ __launch_bounds__(256) void prep_w1(const float* __restrict__ W1,
                                               unsigned short* __restrict__ Wg) {
    int idx = blockIdx.x * 256 + threadIdx.x;   // 0 .. 32767
    if (idx >= F_IN * HID) return;
    int k = idx >> 6, n = idx & 63;
    unsigned short hi, lo;
    split_bf16(W1[idx], hi, lo);
    int nt = n >> 4, kc = k >> 5;
    int l  = ((k >> 3) & 3) * 16 + (n & 15);
    int j  = k & 7;
    long base = ((((long)nt * 16 + kc) * 2) * 64 + l) * 8 + j;
    Wg[base]       = hi;
    Wg[base + 512] = lo;
}

// ---------------------------------------------------------------------------
// GEMM1: support = x @ W1 via split-bf16 MFMA. 128-row tile, BK=128 K-tile.
// x staged fp32 via global_load_lds; 16B-chunk XOR swizzle (inverse on src).
// ---------------------------------------------------------------------------
__global__ __launch_bounds__(256, 2) void gemm1_mfma(const float* __restrict__ x,
                                                     const unsigned short* __restrict__ Wg,
                                                     float* __restrict__ support) {
    __shared__ float tile[BM * BK];   // 64 KB

    const int tid  = threadIdx.x;
    const int l    = tid & 63;
    const int w    = tid >> 6;
    const int lr   = l & 15;
    const int lg   = l >> 4;
    const int row0 = blockIdx.x * BM;

    f32x4 acc[2][4] = {};

    for (int kb = 0; kb < F_IN; kb += BK) {
        // --- stage: 128 rows x 32 chunks = 4096 16B slots ---
        #pragma unroll
        for (int j = 0; j < 16; j++) {
            int slotbase = j * 256 + w * 64;        // wave-uniform
            int slot     = slotbase + l;
            int row      = slot >> 5;               // 32 chunks per row
            int cl       = (slot & 31) ^ (row & 7); // inverse swizzle on src
            int rr       = row0 + row;
            if (rr > N_NODES - 1) rr = N_NODES - 1; // clamp (rows >= N discarded)
            gload_lds16(x + (long)rr * F_IN + kb + cl * 4, tile + slotbase * 4);
        }
        __syncthreads();

        #pragma unroll
        for (int ks = 0; ks < 4; ks++) {
            int kc = (kb >> 5) + ks;
            short8 ah[2], al[2];
            #pragma unroll
            for (int m = 0; m < 2; m++) {
                int r  = m * 64 + w * 16 + lr;
                int c0 = ks * 8 + lg * 2;
                f32x4 v0 = *(const f32x4*)&tile[r * BK + ((c0 ^ (r & 7)) << 2)];
                f32x4 v1 = *(const f32x4*)&tile[r * BK + (((c0 + 1) ^ (r & 7)) << 2)];
                split8(v0, v1, ah[m], al[m]);
            }
            #pragma unroll
            for (int nt = 0; nt < 4; nt++) {
                long bo = ((((long)nt * 16 + kc) * 2) * 64 + l) * 8;
                short8 bh = *(const short8*)(Wg + bo);
                short8 bl = *(const short8*)(Wg + bo + 512);
                #pragma unroll
                for (int m = 0; m < 2; m++) {
                    acc[m][nt] = __builtin_amdgcn_mfma_f32_16x16x32_bf16(ah[m], bh, acc[m][nt], 0, 0, 0);
                    acc[m][nt] = __builtin_amdgcn_mfma_f32_16x16x32_bf16(ah[m], bl, acc[m][nt], 0, 0, 0);
                    acc[m][nt] = __builtin_amdgcn_mfma_f32_16x16x32_bf16(al[m], bh, acc[m][nt], 0, 0, 0);
                }
            }
        }
        __syncthreads();
    }

    // epilogue: C/D layout col = lane&15, row = (lane>>4)*4 + reg
    #pragma unroll
    for (int m = 0; m < 2; m++) {
        #pragma unroll
        for (int nt = 0; nt < 4; nt++) {
            #pragma unroll
            for (int r = 0; r < 4; r++) {
                int row = row0 + m * 64 + w * 16 + lg * 4 + r;
                if (row < N_NODES)
                    support[(long)row * HID + nt * 16 + lr] = acc[m][nt][r];
            }
        }
    }
}

// ---------------------------------------------------------------------------
// SPMM1 + bias + relu + GEMM2 fused, unroll-8 gathers (latency-bound MLP):
//   sup2[n] = relu( sum_e val*sup1[src] + b1 ) @ W2
// ---------------------------------------------------------------------------
__global__ __launch_bounds__(256) void spmm1_fused(const int* __restrict__ off,
                                                   const int2* __restrict__ epk,
                                                   const float* __restrict__ sup,
                                                   const float* __restrict__ b1,
                                                   const float* __restrict__ W2,
                                                   float* __restrict__ sup2) {
    __shared__ float w2s[HID * NCLS];   // [k][c]
    __shared__ float hrow[4][HID];
    int tid = threadIdx.x;
    for (int i = tid; i < HID * NCLS; i += 256) w2s[i] = W2[i];
    __syncthreads();

    int lane = tid & 63;
    int w    = tid >> 6;
    int n    = blockIdx.x * 4 + w;      // grid exact: N_NODES % 4 == 0

    int e0 = off[n];
    int e1 = off[n + 1];
    float acc = 0.f;
    int e = e0;
    for (; e + 7 < e1; e += 8) {
        int2 p[8];
        float g[8];
        #pragma unroll
        for (int j = 0; j < 8; j++) p[j] = epk[e + j];
        #pragma unroll
        for (int j = 0; j < 8; j++) g[j] = sup[(long)p[j].x * HID + lane];
        #pragma unroll
        for (int j = 0; j < 8; j++) acc += __int_as_float(p[j].y) * g[j];
    }
    for (; e + 3 < e1; e += 4) {
        int2 p0 = epk[e],     p1 = epk[e + 1];
        int2 p2 = epk[e + 2], p3 = epk[e + 3];
        float g0 = sup[(long)p0.x * HID + lane];
        float g1 = sup[(long)p1.x * HID + lane];
        float g2 = sup[(long)p2.x * HID + lane];
        float g3 = sup[(long)p3.x * HID + lane];
        acc += __int_as_float(p0.y) * g0 + __int_as_float(p1.y) * g1
             + __int_as_float(p2.y) * g2 + __int_as_float(p3.y) * g3;
    }
    for (; e < e1; e++) {
        int2 p = epk[e];
        acc += __int_as_float(p.y) * sup[(long)p.x * HID + lane];
    }
    float hv = fmaxf(acc + b1[lane], 0.f);

    hrow[w][lane] = hv;
    asm volatile("s_waitcnt lgkmcnt(0)" ::: "memory");   // wave-local LDS drain
    __builtin_amdgcn_sched_barrier(0);                   // rule #18 fence

    int c = lane & 15, q = lane >> 4;
    float part = 0.f;
    #pragma unroll
    for (int k0 = 0; k0 < 16; k0++) {
        int k = q * 16 + k0;
        part += hrow[w][k] * w2s[k * NCLS + c];
    }
    part += __shfl_xor(part, 16);
    part += __shfl_xor(part, 32);
    if (lane < 16) sup2[(long)n * NCLS + c] = part;
}

// ---------------------------------------------------------------------------
// SPMM2 (CSR) fused with +b2 and softmax, unroll-8. 16 lanes per node.
// ---------------------------------------------------------------------------
__global__ __launch_bounds__(256) void spmm2_softmax(const int* __restrict__ off,
                                                     const int2* __restrict__ epk,
                                                     const float* __restrict__ sup2,
                                                     const float* __restrict__ b2,
                                                     float* __restrict__ out) {
    int tid = threadIdx.x;
    int n   = blockIdx.x * 16 + (tid >> 4);
    int c   = tid & 15;
    if (n >= N_NODES) return;

    int e0 = off[n];
    int e1 = off[n + 1];
    float acc = 0.f;
    int e = e0;
    for (; e + 7 < e1; e += 8) {
        int2 p[8];
        float g[8];
        #pragma unroll
        for (int j = 0; j < 8; j++) p[j] = epk[e + j];
        #pragma unroll
        for (int j = 0; j < 8; j++) g[j] = sup2[(long)p[j].x * NCLS + c];
        #pragma unroll
        for (int j = 0; j < 8; j++) acc += __int_as_float(p[j].y) * g[j];
    }
    for (; e + 3 < e1; e += 4) {
        int2 p0 = epk[e],     p1 = epk[e + 1];
        int2 p2 = epk[e + 2], p3 = epk[e + 3];
        float g0 = sup2[(long)p0.x * NCLS + c];
        float g1 = sup2[(long)p1.x * NCLS + c];
        float g2 = sup2[(long)p2.x * NCLS + c];
        float g3 = sup2[(long)p3.x * NCLS + c];
        acc += __int_as_float(p0.y) * g0 + __int_as_float(p1.y) * g1
             + __int_as_float(p2.y) * g2 + __int_as_float(p3.y) * g3;
    }
    for (; e < e1; e++) {
        int2 p = epk[e];
        acc += __int_as_float(p.y) * sup2[(long)p.x * NCLS + c];
    }

    float lg = acc + b2[c];
    float m = lg;
    #pragma unroll
    for (int mask = 1; mask < 16; mask <<= 1)
        m = fmaxf(m, __shfl_xor(m, mask, 16));
    float p = expf(lg - m);
    float s = p;
    #pragma unroll
    for (int mask = 1; mask < 16; mask <<= 1)
        s += __shfl_xor(s, mask, 16);
    out[(long)n * NCLS + c] = p / s;
}

// ---------------------------------------------------------------------------
extern "C" void kernel_launch(void* const* d_in, const int* in_sizes, int n_in,
                              void* d_out, int out_size, void* d_ws, size_t ws_size,
                              hipStream_t stream) {
    const float* x     = (const float*)d_in[0];
    const int*   esrc  = (const int*)  d_in[1];
    const int*   edst  = (const int*)  d_in[2];
    const float* eval_ = (const float*)d_in[3];
    const float* W1    = (const float*)d_in[4];
    const float* b1    = (const float*)d_in[5];
    const float* W2    = (const float*)d_in[6];
    const float* b2    = (const float*)d_in[7];
    float* out = (float*)d_out;

    // workspace layout (4B units; every base 16B-aligned)
    float* sup1  = (float*)d_ws;                        // 6,400,000 f
    float* sup2  = sup1 + (long)N_NODES * HID;          // 1,600,000 f
    int2*  epk   = (int2*)(sup2 + (long)N_NODES * NCLS);// 1,600,000 int2
    int*   off   = (int*)(epk + N_EDGES);               // 100,004 i
    int*   bsums = off + 100004;                        // 128 i
    int*   bbase = bsums + 128;                         // 128 i
    int*   bh    = bbase + 128;                         // 38,320 i (98x391)
    unsigned short* Wg = (unsigned short*)(bh + 38320); // 65,536 us (128 KB)
    int2*  mid   = (int2*)(Wg + 65536);                 // 1,600,000 int2

    // --- CSR build (scan-based, no global atomics) ---
    bhist  <<<PA_NB,   256, 0, stream>>>(edst, bh);
    colscan<<<SCAN_NB, 512, 0, stream>>>(bh, bsums);
    scan_top<<<1,      128, 0, stream>>>(bsums, bbase, off);
    partA2 <<<PA_NB,   256, 0, stream>>>(esrc, edst, eval_, bh, bbase, mid);
    partB2 <<<SCAN_NB, 512, 0, stream>>>(bbase, bsums, mid, epk, off);

    // --- W1 fragment prep + layer 1 ---
    prep_w1<<<(F_IN * HID + 255) / 256, 256, 0, stream>>>(W1, Wg);
    gemm1_mfma<<<(N_NODES + BM - 1) / BM, 256, 0, stream>>>(x, Wg, sup1);
    spmm1_fused<<<N_NODES / 4, 256, 0, stream>>>(off, epk, sup1, b1, W2, sup2);

    // --- layer 2 + softmax ---
    spmm2_softmax<<<(N_NODES + 15) / 16, 256, 0, stream>>>(off, epk, sup2, b2, out);
}